// Round 1
// baseline (915.289 us; speedup 1.0000x reference)
//
#include <hip/hip_runtime.h>
#include <math.h>

#define D 64

static __device__ __forceinline__ unsigned short f2bf(float f) {
    unsigned int u = __float_as_uint(f);
    unsigned int r = (u + 0x7FFFu + ((u >> 16) & 1u)) >> 16;  // RNE
    return (unsigned short)r;
}
static __device__ __forceinline__ float bf2f(unsigned short h) {
    return __uint_as_float(((unsigned int)h) << 16);
}

// ---------------- proj GEMM: proj[n,r,o] = sum_d feat[n,d] * W[r,d,o] (bf16 out)
__global__ __launch_bounds__(256) void k_proj(const float* __restrict__ feat,
                                              const float* __restrict__ W,
                                              unsigned short* __restrict__ proj,
                                              int N, int R) {
    const int r  = blockIdx.y;
    const int n0 = blockIdx.x * 64;
    __shared__ float As[64][65];   // feat tile [node][d]
    __shared__ float Bs[64][68];   // W_r [d][o], pad 68 for aligned float4
    const int t = threadIdx.x;
    for (int idx = t; idx < 64 * 64; idx += 256) {
        int row = idx >> 6, col = idx & 63;
        int n = n0 + row;
        As[row][col] = (n < N) ? feat[n * D + col] : 0.f;
    }
    const float* Wr = W + (size_t)r * D * D;
    for (int idx = t; idx < 64 * 64; idx += 256) {
        int row = idx >> 6, col = idx & 63;
        Bs[row][col] = Wr[idx];
    }
    __syncthreads();
    const int tx = t & 15, ty = t >> 4;
    const int r0 = ty * 4, c0 = tx * 4;
    float acc[4][4] = {};
    for (int k = 0; k < 64; ++k) {
        float a0 = As[r0 + 0][k];
        float a1 = As[r0 + 1][k];
        float a2 = As[r0 + 2][k];
        float a3 = As[r0 + 3][k];
        float4 b = *(const float4*)&Bs[k][c0];
        acc[0][0] += a0 * b.x; acc[0][1] += a0 * b.y; acc[0][2] += a0 * b.z; acc[0][3] += a0 * b.w;
        acc[1][0] += a1 * b.x; acc[1][1] += a1 * b.y; acc[1][2] += a1 * b.z; acc[1][3] += a1 * b.w;
        acc[2][0] += a2 * b.x; acc[2][1] += a2 * b.y; acc[2][2] += a2 * b.z; acc[2][3] += a2 * b.w;
        acc[3][0] += a3 * b.x; acc[3][1] += a3 * b.y; acc[3][2] += a3 * b.z; acc[3][3] += a3 * b.w;
    }
    for (int i = 0; i < 4; ++i) {
        int n = n0 + r0 + i;
        if (n < N) {
            size_t off = ((size_t)n * R + r) * D + c0;
            unsigned int lo = (unsigned int)f2bf(acc[i][0]) | ((unsigned int)f2bf(acc[i][1]) << 16);
            unsigned int hi = (unsigned int)f2bf(acc[i][2]) | ((unsigned int)f2bf(acc[i][3]) << 16);
            *(uint2*)&proj[off] = make_uint2(lo, hi);
        }
    }
}

// ---------------- histogram of dst
__global__ __launch_bounds__(256) void k_hist(const int* __restrict__ dst, int* __restrict__ deg, int E) {
    int e = blockIdx.x * 256 + threadIdx.x;
    if (e < E) atomicAdd(&deg[dst[e]], 1);
}

// ---------------- scan step 1: per-1024 block inclusive scan
__global__ __launch_bounds__(1024) void k_scan1(const int* __restrict__ deg, int* __restrict__ tscan,
                                                int* __restrict__ bsum, int N) {
    __shared__ int s[1024];
    const int t = threadIdx.x;
    const int i = blockIdx.x * 1024 + t;
    int v = (i < N) ? deg[i] : 0;
    s[t] = v;
    __syncthreads();
    for (int off = 1; off < 1024; off <<= 1) {
        int tmp = (t >= off) ? s[t - off] : 0;
        __syncthreads();
        s[t] += tmp;
        __syncthreads();
    }
    if (i < N) tscan[i] = s[t];
    if (t == 1023) bsum[blockIdx.x] = s[1023];
}

// ---------------- scan step 2: serial exclusive scan of block sums (NB ~ 98)
__global__ void k_scan2(const int* __restrict__ bsum, int* __restrict__ bofs, int NB) {
    if (threadIdx.x == 0 && blockIdx.x == 0) {
        int run = 0;
        for (int b = 0; b < NB; ++b) { bofs[b] = run; run += bsum[b]; }
    }
}

// ---------------- scan step 3: final offsets + scatter cursor
__global__ __launch_bounds__(256) void k_scan3(const int* __restrict__ tscan, const int* __restrict__ bofs,
                                               int* __restrict__ offsets, int* __restrict__ cursor, int N) {
    int i = blockIdx.x * 256 + threadIdx.x;
    if (i <= N) {
        int v = (i == 0) ? 0 : (tscan[i - 1] + bofs[(i - 1) >> 10]);
        offsets[i] = v;
        if (i < N) cursor[i] = v;
    }
}

// ---------------- scatter edges into dst-sorted order (src | etype<<20 packed)
__global__ __launch_bounds__(256) void k_scatter(const int* __restrict__ src, const int* __restrict__ dst,
                                                 const int* __restrict__ etype, int* __restrict__ cursor,
                                                 int* __restrict__ spack, int E) {
    int e = blockIdx.x * 256 + threadIdx.x;
    if (e < E) {
        int d = dst[e];
        int p = atomicAdd(&cursor[d], 1);
        spack[p] = src[e] | (etype[e] << 20);
    }
}

// ---------------- fused att + edge-softmax + aggregation: one wave per dst node
__global__ __launch_bounds__(256) void k_fused(const unsigned short* __restrict__ proj,
                                               const float* __restrict__ feat,
                                               const float* __restrict__ emb,
                                               const int* __restrict__ offsets,
                                               const int* __restrict__ spack,
                                               float* __restrict__ h_nb,
                                               int N, int R) {
    const int lane = threadIdx.x & 63;
    const int wav  = threadIdx.x >> 6;
    const int n = blockIdx.x * 4 + wav;
    if (n >= N) return;
    const int beg = offsets[n], end = offsets[n + 1];
    const size_t RD = (size_t)R * D;
    float m = -INFINITY, l = 0.f, acc = 0.f;
    for (int i = beg; i < end; ++i) {
        int pk = spack[i];
        int sv = pk & 0xFFFFF;
        int et = pk >> 20;
        float tt = bf2f(proj[(size_t)sv * RD + et * D + lane]);
        float hh = bf2f(proj[(size_t)n * RD + et * D + lane]);
        float em = emb[et * D + lane];
        float u = tanhf(hh + em);
        float p = tt * u;
        #pragma unroll
        for (int off = 32; off > 0; off >>= 1) p += __shfl_xor(p, off, 64);
        float att = p;
        float nm = fmaxf(m, att);
        float scale = __expf(m - nm);    // m=-inf on first edge -> 0
        float wgt   = __expf(att - nm);
        l = l * scale + wgt;
        float fs = feat[sv * D + lane];
        acc = acc * scale + wgt * fs;
        m = nm;
    }
    h_nb[(size_t)n * D + lane] = (end > beg) ? (acc / l) : 0.f;
}

// ---------------- final: out = lrelu((f+h)@W1^T) + lrelu((f*h)@W2^T)
__global__ __launch_bounds__(256) void k_final(const float* __restrict__ feat,
                                               const float* __restrict__ h_nb,
                                               const float* __restrict__ W1,
                                               const float* __restrict__ W2,
                                               float* __restrict__ out, int N) {
    __shared__ float W1s[64][65];
    __shared__ float W2s[64][65];
    const int t = threadIdx.x;
    for (int idx = t; idx < 64 * 64; idx += 256) {
        int row = idx >> 6, col = idx & 63;
        W1s[row][col] = W1[idx];
        W2s[row][col] = W2[idx];
    }
    __syncthreads();
    const int lane = t & 63;
    const int wav  = t >> 6;
    for (int n = blockIdx.x * 4 + wav; n < N; n += gridDim.x * 4) {
        float f = feat[(size_t)n * D + lane];
        float h = h_nb[(size_t)n * D + lane];
        float xs = f + h;
        float xp = f * h;
        float a1 = 0.f, a2 = 0.f;
        #pragma unroll
        for (int d = 0; d < 64; ++d) {
            float s1 = __shfl(xs, d, 64);
            float s2 = __shfl(xp, d, 64);
            a1 += s1 * W1s[lane][d];
            a2 += s2 * W2s[lane][d];
        }
        float o1 = (a1 > 0.f) ? a1 : 0.01f * a1;
        float o2 = (a2 > 0.f) ? a2 : 0.01f * a2;
        out[(size_t)n * D + lane] = o1 + o2;
    }
}

extern "C" void kernel_launch(void* const* d_in, const int* in_sizes, int n_in,
                              void* d_out, int out_size, void* d_ws, size_t ws_size,
                              hipStream_t stream) {
    const float* feat  = (const float*)d_in[0];
    const float* relW  = (const float*)d_in[1];
    const float* relE  = (const float*)d_in[2];
    const float* W1    = (const float*)d_in[3];
    const float* W2    = (const float*)d_in[4];
    const int*   src   = (const int*)d_in[5];
    const int*   dst   = (const int*)d_in[6];
    const int*   etype = (const int*)d_in[7];
    float* out = (float*)d_out;

    const int N = in_sizes[0] / D;
    const int R = in_sizes[2] / D;
    const int E = in_sizes[5];

    // workspace carve-up (256B aligned)
    char* w = (char*)d_ws;
    size_t off = 0;
    auto alloc = [&](size_t bytes) -> void* {
        void* p = w + off;
        off = (off + bytes + 255) & ~(size_t)255;
        return p;
    };
    unsigned short* proj = (unsigned short*)alloc((size_t)N * R * D * sizeof(unsigned short));
    float* h_nb   = (float*)alloc((size_t)N * D * sizeof(float));
    int* offsets  = (int*)alloc((size_t)(N + 1) * sizeof(int));
    int* tscan    = (int*)alloc((size_t)N * sizeof(int));
    int* cursor   = (int*)alloc((size_t)N * sizeof(int));
    int* deg      = (int*)alloc((size_t)N * sizeof(int));
    int* bsum     = (int*)alloc(2048 * sizeof(int));
    int* bofs     = (int*)alloc(2048 * sizeof(int));
    int* spack    = (int*)alloc((size_t)E * sizeof(int));
    (void)ws_size; (void)n_in; (void)out_size;

    const int NB = (N + 1023) / 1024;

    hipMemsetAsync(deg, 0, (size_t)N * sizeof(int), stream);
    k_hist<<<(E + 255) / 256, 256, 0, stream>>>(dst, deg, E);
    k_scan1<<<NB, 1024, 0, stream>>>(deg, tscan, bsum, N);
    k_scan2<<<1, 64, 0, stream>>>(bsum, bofs, NB);
    k_scan3<<<(N + 1 + 255) / 256, 256, 0, stream>>>(tscan, bofs, offsets, cursor, N);
    k_scatter<<<(E + 255) / 256, 256, 0, stream>>>(src, dst, etype, cursor, spack, E);
    dim3 pg((N + 63) / 64, R);
    k_proj<<<pg, 256, 0, stream>>>(feat, relW, proj, N, R);
    k_fused<<<(N + 3) / 4, 256, 0, stream>>>(proj, feat, relE, offsets, spack, h_nb, N, R);
    k_final<<<1024, 256, 0, stream>>>(feat, h_nb, W1, W2, out, N);
}

// Round 2
// 773.970 us; speedup vs baseline: 1.1826x; 1.1826x over previous
//
#include <hip/hip_runtime.h>
#include <math.h>

#define D 64

typedef __attribute__((ext_vector_type(8))) short bf16x8;
typedef __attribute__((ext_vector_type(4))) float f32x4;

static __device__ __forceinline__ unsigned short f2bf(float f) {
    unsigned int u = __float_as_uint(f);
    unsigned int r = (u + 0x7FFFu + ((u >> 16) & 1u)) >> 16;  // RNE
    return (unsigned short)r;
}
static __device__ __forceinline__ float bf2f(unsigned short h) {
    return __uint_as_float(((unsigned int)h) << 16);
}

// ---------------- proj GEMM via MFMA, split-bf16 (hi+lo) for ~fp32 accuracy.
// proj[n,r,o] = sum_d feat[n,d] * W[r,d,o], stored bf16.
// Block: 128 nodes x one r. 4 waves; wave w does rows [w*32, w*32+32).
__global__ __launch_bounds__(256, 2) void k_proj(const float* __restrict__ feat,
                                                 const float* __restrict__ W,
                                                 unsigned short* __restrict__ proj,
                                                 int N, int R) {
    const int r  = blockIdx.y;
    const int n0 = blockIdx.x * 128;
    __shared__ unsigned short Ah[128 * 72];   // feat hi, [row][d], pad 72
    __shared__ unsigned short Al[128 * 72];   // feat lo
    __shared__ unsigned short Bh[64 * 72];    // W^T hi: [o][d]
    __shared__ unsigned short Bl[64 * 72];    // W^T lo
    const int t = threadIdx.x;

    // stage A: 128x64 floats = 2048 float4, split to hi/lo bf16
    const float4* f4 = (const float4*)feat;
    #pragma unroll
    for (int p = 0; p < 8; ++p) {
        int idx = p * 256 + t;
        int row = idx >> 4, c4 = idx & 15;
        int n = n0 + row;
        float4 v = make_float4(0.f, 0.f, 0.f, 0.f);
        if (n < N) v = f4[(size_t)n * 16 + c4];
        unsigned short h0 = f2bf(v.x), h1 = f2bf(v.y), h2 = f2bf(v.z), h3 = f2bf(v.w);
        unsigned short l0 = f2bf(v.x - bf2f(h0)), l1 = f2bf(v.y - bf2f(h1));
        unsigned short l2 = f2bf(v.z - bf2f(h2)), l3 = f2bf(v.w - bf2f(h3));
        ushort4 hh; hh.x = h0; hh.y = h1; hh.z = h2; hh.w = h3;
        ushort4 ll; ll.x = l0; ll.y = l1; ll.z = l2; ll.w = l3;
        *(ushort4*)&Ah[row * 72 + c4 * 4] = hh;
        *(ushort4*)&Al[row * 72 + c4 * 4] = ll;
    }
    // stage B with transpose: W_r is [d][o]; store BsT[o][d]
    const float4* w4 = (const float4*)(W + (size_t)r * D * D);
    #pragma unroll
    for (int p = 0; p < 4; ++p) {
        int idx = p * 256 + t;
        int d = idx >> 4, c4 = idx & 15;
        float4 v = w4[idx];
        float vals[4] = {v.x, v.y, v.z, v.w};
        #pragma unroll
        for (int j = 0; j < 4; ++j) {
            int o = c4 * 4 + j;
            unsigned short h = f2bf(vals[j]);
            unsigned short l = f2bf(vals[j] - bf2f(h));
            Bh[o * 72 + d] = h;
            Bl[o * 72 + d] = l;
        }
    }
    __syncthreads();

    const int lane = t & 63;
    const int w    = t >> 6;
    const int m    = lane & 15;   // row-in-tile (A), col-in-tile (B/C)
    const int q    = lane >> 4;   // quad: k-chunk selector

    // A frags: 2 row-strips x 2 k-blocks, hi+lo
    bf16x8 ah[2][2], al[2][2];
    #pragma unroll
    for (int s = 0; s < 2; ++s)
        #pragma unroll
        for (int kb = 0; kb < 2; ++kb) {
            int row = w * 32 + s * 16 + m;
            ah[s][kb] = *(const bf16x8*)&Ah[row * 72 + kb * 32 + q * 8];
            al[s][kb] = *(const bf16x8*)&Al[row * 72 + kb * 32 + q * 8];
        }

    f32x4 acc[4][2];
    #pragma unroll
    for (int c = 0; c < 4; ++c)
        #pragma unroll
        for (int s = 0; s < 2; ++s)
            acc[c][s] = (f32x4){0.f, 0.f, 0.f, 0.f};

    #pragma unroll
    for (int c = 0; c < 4; ++c) {
        #pragma unroll
        for (int kb = 0; kb < 2; ++kb) {
            int col = c * 16 + m;
            bf16x8 bh = *(const bf16x8*)&Bh[col * 72 + kb * 32 + q * 8];
            bf16x8 bl = *(const bf16x8*)&Bl[col * 72 + kb * 32 + q * 8];
            #pragma unroll
            for (int s = 0; s < 2; ++s) {
                acc[c][s] = __builtin_amdgcn_mfma_f32_16x16x32_bf16(ah[s][kb], bh, acc[c][s], 0, 0, 0);
                acc[c][s] = __builtin_amdgcn_mfma_f32_16x16x32_bf16(al[s][kb], bh, acc[c][s], 0, 0, 0);
                acc[c][s] = __builtin_amdgcn_mfma_f32_16x16x32_bf16(ah[s][kb], bl, acc[c][s], 0, 0, 0);
            }
        }
    }

    // store: C/D layout col=lane&15, row=quad*4+reg
    #pragma unroll
    for (int s = 0; s < 2; ++s)
        #pragma unroll
        for (int i = 0; i < 4; ++i) {
            int row = w * 32 + s * 16 + q * 4 + i;
            int n = n0 + row;
            if (n < N) {
                size_t base = ((size_t)n * R + r) * D;
                #pragma unroll
                for (int c = 0; c < 4; ++c)
                    proj[base + c * 16 + m] = f2bf(acc[c][s][i]);
            }
        }
}

// ---------------- histogram of dst
__global__ __launch_bounds__(256) void k_hist(const int* __restrict__ dst, int* __restrict__ deg, int E) {
    int e = blockIdx.x * 256 + threadIdx.x;
    if (e < E) atomicAdd(&deg[dst[e]], 1);
}

// ---------------- scan step 1: per-1024 block inclusive scan
__global__ __launch_bounds__(1024) void k_scan1(const int* __restrict__ deg, int* __restrict__ tscan,
                                                int* __restrict__ bsum, int N) {
    __shared__ int s[1024];
    const int t = threadIdx.x;
    const int i = blockIdx.x * 1024 + t;
    int v = (i < N) ? deg[i] : 0;
    s[t] = v;
    __syncthreads();
    for (int off = 1; off < 1024; off <<= 1) {
        int tmp = (t >= off) ? s[t - off] : 0;
        __syncthreads();
        s[t] += tmp;
        __syncthreads();
    }
    if (i < N) tscan[i] = s[t];
    if (t == 1023) bsum[blockIdx.x] = s[1023];
}

// ---------------- scan step 2: parallel exclusive scan of block sums
__global__ __launch_bounds__(1024) void k_scan2(const int* __restrict__ bsum, int* __restrict__ bofs, int NB) {
    __shared__ int s[1024];
    const int t = threadIdx.x;
    int carry = 0;
    for (int b0 = 0; b0 < NB; b0 += 1024) {
        int i = b0 + t;
        int v = (i < NB) ? bsum[i] : 0;
        s[t] = v;
        __syncthreads();
        for (int off = 1; off < 1024; off <<= 1) {
            int tmp = (t >= off) ? s[t - off] : 0;
            __syncthreads();
            s[t] += tmp;
            __syncthreads();
        }
        if (i < NB) bofs[i] = carry + s[t] - v;  // exclusive
        int tot = s[1023];
        __syncthreads();
        carry += tot;
    }
}

// ---------------- scan step 3: final offsets + scatter cursor
__global__ __launch_bounds__(256) void k_scan3(const int* __restrict__ tscan, const int* __restrict__ bofs,
                                               int* __restrict__ offsets, int* __restrict__ cursor, int N) {
    int i = blockIdx.x * 256 + threadIdx.x;
    if (i <= N) {
        int v = (i == 0) ? 0 : (tscan[i - 1] + bofs[(i - 1) >> 10]);
        offsets[i] = v;
        if (i < N) cursor[i] = v;
    }
}

// ---------------- scatter edges into dst-sorted order (src | etype<<20 packed)
__global__ __launch_bounds__(256) void k_scatter(const int* __restrict__ src, const int* __restrict__ dst,
                                                 const int* __restrict__ etype, int* __restrict__ cursor,
                                                 int* __restrict__ spack, int E) {
    int e = blockIdx.x * 256 + threadIdx.x;
    if (e < E) {
        int d = dst[e];
        int p = atomicAdd(&cursor[d], 1);
        spack[p] = src[e] | (etype[e] << 20);
    }
}

// ---------------- fused att + edge-softmax + aggregation: one wave per dst node
__global__ __launch_bounds__(256) void k_fused(const unsigned short* __restrict__ proj,
                                               const float* __restrict__ feat,
                                               const float* __restrict__ emb,
                                               const int* __restrict__ offsets,
                                               const int* __restrict__ spack,
                                               float* __restrict__ h_nb,
                                               int N, int R) {
    const int lane = threadIdx.x & 63;
    const int wav  = threadIdx.x >> 6;
    const int n = blockIdx.x * 4 + wav;
    if (n >= N) return;
    const int beg = offsets[n], end = offsets[n + 1];
    const size_t RD = (size_t)R * D;
    float m = -INFINITY, l = 0.f, acc = 0.f;
    for (int i = beg; i < end; ++i) {
        int pk = spack[i];
        int sv = pk & 0xFFFFF;
        int et = pk >> 20;
        float tt = bf2f(proj[(size_t)sv * RD + et * D + lane]);
        float hh = bf2f(proj[(size_t)n * RD + et * D + lane]);
        float em = emb[et * D + lane];
        float u = tanhf(hh + em);
        float p = tt * u;
        #pragma unroll
        for (int off = 32; off > 0; off >>= 1) p += __shfl_xor(p, off, 64);
        float att = p;
        float nm = fmaxf(m, att);
        float scale = __expf(m - nm);    // m=-inf on first edge -> 0
        float wgt   = __expf(att - nm);
        l = l * scale + wgt;
        float fs = feat[sv * D + lane];
        acc = acc * scale + wgt * fs;
        m = nm;
    }
    h_nb[(size_t)n * D + lane] = (end > beg) ? (acc / l) : 0.f;
}

// ---------------- final: out = lrelu((f+h)@W1^T) + lrelu((f*h)@W2^T)
__global__ __launch_bounds__(256) void k_final(const float* __restrict__ feat,
                                               const float* __restrict__ h_nb,
                                               const float* __restrict__ W1,
                                               const float* __restrict__ W2,
                                               float* __restrict__ out, int N) {
    __shared__ float W1s[64][65];
    __shared__ float W2s[64][65];
    const int t = threadIdx.x;
    for (int idx = t; idx < 64 * 64; idx += 256) {
        int row = idx >> 6, col = idx & 63;
        W1s[row][col] = W1[idx];
        W2s[row][col] = W2[idx];
    }
    __syncthreads();
    const int lane = t & 63;
    const int wav  = t >> 6;
    for (int n = blockIdx.x * 4 + wav; n < N; n += gridDim.x * 4) {
        float f = feat[(size_t)n * D + lane];
        float h = h_nb[(size_t)n * D + lane];
        float xs = f + h;
        float xp = f * h;
        float a1 = 0.f, a2 = 0.f;
        #pragma unroll
        for (int d = 0; d < 64; ++d) {
            float s1 = __shfl(xs, d, 64);
            float s2 = __shfl(xp, d, 64);
            a1 += s1 * W1s[lane][d];
            a2 += s2 * W2s[lane][d];
        }
        float o1 = (a1 > 0.f) ? a1 : 0.01f * a1;
        float o2 = (a2 > 0.f) ? a2 : 0.01f * a2;
        out[(size_t)n * D + lane] = o1 + o2;
    }
}

extern "C" void kernel_launch(void* const* d_in, const int* in_sizes, int n_in,
                              void* d_out, int out_size, void* d_ws, size_t ws_size,
                              hipStream_t stream) {
    const float* feat  = (const float*)d_in[0];
    const float* relW  = (const float*)d_in[1];
    const float* relE  = (const float*)d_in[2];
    const float* W1    = (const float*)d_in[3];
    const float* W2    = (const float*)d_in[4];
    const int*   src   = (const int*)d_in[5];
    const int*   dst   = (const int*)d_in[6];
    const int*   etype = (const int*)d_in[7];
    float* out = (float*)d_out;

    const int N = in_sizes[0] / D;
    const int R = in_sizes[2] / D;
    const int E = in_sizes[5];

    // workspace carve-up (256B aligned)
    char* w = (char*)d_ws;
    size_t off = 0;
    auto alloc = [&](size_t bytes) -> void* {
        void* p = w + off;
        off = (off + bytes + 255) & ~(size_t)255;
        return p;
    };
    unsigned short* proj = (unsigned short*)alloc((size_t)N * R * D * sizeof(unsigned short));
    float* h_nb   = (float*)alloc((size_t)N * D * sizeof(float));
    int* offsets  = (int*)alloc((size_t)(N + 1) * sizeof(int));
    int* tscan    = (int*)alloc((size_t)N * sizeof(int));
    int* cursor   = (int*)alloc((size_t)N * sizeof(int));
    int* deg      = (int*)alloc((size_t)N * sizeof(int));
    int* bsum     = (int*)alloc(2048 * sizeof(int));
    int* bofs     = (int*)alloc(2048 * sizeof(int));
    int* spack    = (int*)alloc((size_t)E * sizeof(int));
    (void)ws_size; (void)n_in; (void)out_size;

    const int NB = (N + 1023) / 1024;

    hipMemsetAsync(deg, 0, (size_t)N * sizeof(int), stream);
    k_hist<<<(E + 255) / 256, 256, 0, stream>>>(dst, deg, E);
    k_scan1<<<NB, 1024, 0, stream>>>(deg, tscan, bsum, N);
    k_scan2<<<1, 1024, 0, stream>>>(bsum, bofs, NB);
    k_scan3<<<(N + 1 + 255) / 256, 256, 0, stream>>>(tscan, bofs, offsets, cursor, N);
    k_scatter<<<(E + 255) / 256, 256, 0, stream>>>(src, dst, etype, cursor, spack, E);
    dim3 pg((N + 127) / 128, R);
    k_proj<<<pg, 256, 0, stream>>>(feat, relW, proj, N, R);
    k_fused<<<(N + 3) / 4, 256, 0, stream>>>(proj, feat, relE, offsets, spack, h_nb, N, R);
    k_final<<<1024, 256, 0, stream>>>(feat, h_nb, W1, W2, out, N);
}

// Round 3
// 765.038 us; speedup vs baseline: 1.1964x; 1.0117x over previous
//
#include <hip/hip_runtime.h>
#include <math.h>

#define D 64

typedef __attribute__((ext_vector_type(8))) short bf16x8;
typedef __attribute__((ext_vector_type(4))) float f32x4;

static __device__ __forceinline__ unsigned short f2bf(float f) {
    unsigned int u = __float_as_uint(f);
    unsigned int r = (u + 0x7FFFu + ((u >> 16) & 1u)) >> 16;  // RNE
    return (unsigned short)r;
}
static __device__ __forceinline__ float bf2f(unsigned short h) {
    return __uint_as_float(((unsigned int)h) << 16);
}
static __device__ __forceinline__ float fast_tanh(float x) {
    x = fminf(fmaxf(x, -15.f), 15.f);
    float e = __expf(2.f * x);
    return (e - 1.f) / (e + 1.f);
}

// ---------------- fused: P = feat@W_r (split-bf16 MFMA, fp32), u = tanh(P+emb),
//                  V = u @ W_r^T (split-W MFMA), V stored bf16. proj never materialized.
// Block: 128 nodes x one r. 4 waves; wave w does rows [w*32, w*32+32).
__global__ __launch_bounds__(256, 2) void k_projv(const float* __restrict__ feat,
                                                  const float* __restrict__ W,
                                                  const float* __restrict__ emb,
                                                  unsigned short* __restrict__ V,
                                                  int N, int R) {
    const int r  = blockIdx.y;
    const int n0 = blockIdx.x * 128;
    // LDS carve: phase1: Ah|Al (128x72 each) + BtH|BtL (64x72, W^T) + WnH|WnL (64x72, W natural)
    // phase2: Us (128x72 bf16) reuses the A region.
    __shared__ unsigned short smem[36864];  // 73728 B
    unsigned short* Ah  = smem;              // 128*72 = 9216
    unsigned short* Al  = Ah  + 9216;
    unsigned short* BtH = Al  + 9216;        // 64*72 = 4608
    unsigned short* BtL = BtH + 4608;
    unsigned short* WnH = BtL + 4608;
    unsigned short* WnL = WnH + 4608;
    unsigned short* Us  = smem;              // reuse (after sync)
    const int t = threadIdx.x;

    // stage A: 128x64 floats, split hi/lo bf16
    const float4* f4 = (const float4*)feat;
    #pragma unroll
    for (int p = 0; p < 8; ++p) {
        int idx = p * 256 + t;
        int row = idx >> 4, c4 = idx & 15;
        int n = n0 + row;
        float4 v = make_float4(0.f, 0.f, 0.f, 0.f);
        if (n < N) v = f4[(size_t)n * 16 + c4];
        unsigned short h0 = f2bf(v.x), h1 = f2bf(v.y), h2 = f2bf(v.z), h3 = f2bf(v.w);
        ushort4 hh; hh.x = h0; hh.y = h1; hh.z = h2; hh.w = h3;
        ushort4 ll;
        ll.x = f2bf(v.x - bf2f(h0)); ll.y = f2bf(v.y - bf2f(h1));
        ll.z = f2bf(v.z - bf2f(h2)); ll.w = f2bf(v.w - bf2f(h3));
        *(ushort4*)&Ah[row * 72 + c4 * 4] = hh;
        *(ushort4*)&Al[row * 72 + c4 * 4] = ll;
    }
    // stage W_r both ways: Bt = W^T [o][d] (for GEMM1), Wn = W natural [d][o] (for GEMM2)
    const float4* w4 = (const float4*)(W + (size_t)r * D * D);
    #pragma unroll
    for (int p = 0; p < 4; ++p) {
        int idx = p * 256 + t;
        int d = idx >> 4, c4 = idx & 15;
        float4 v = w4[idx];
        float vals[4] = {v.x, v.y, v.z, v.w};
        ushort4 hh, ll;
        unsigned short* hp = (unsigned short*)&hh;
        unsigned short* lp = (unsigned short*)&ll;
        #pragma unroll
        for (int j = 0; j < 4; ++j) {
            int o = c4 * 4 + j;
            unsigned short h = f2bf(vals[j]);
            unsigned short l = f2bf(vals[j] - bf2f(h));
            hp[j] = h; lp[j] = l;
            BtH[o * 72 + d] = h;
            BtL[o * 72 + d] = l;
        }
        *(ushort4*)&WnH[d * 72 + c4 * 4] = hh;
        *(ushort4*)&WnL[d * 72 + c4 * 4] = ll;
    }
    __syncthreads();

    const int lane = t & 63;
    const int w    = t >> 6;
    const int m    = lane & 15;
    const int q    = lane >> 4;

    // ---------- GEMM1: P[row][o] = sum_d feat*W
    bf16x8 ah[2][2], al[2][2];
    #pragma unroll
    for (int s = 0; s < 2; ++s)
        #pragma unroll
        for (int kb = 0; kb < 2; ++kb) {
            int row = w * 32 + s * 16 + m;
            ah[s][kb] = *(const bf16x8*)&Ah[row * 72 + kb * 32 + q * 8];
            al[s][kb] = *(const bf16x8*)&Al[row * 72 + kb * 32 + q * 8];
        }
    f32x4 acc[4][2];
    #pragma unroll
    for (int c = 0; c < 4; ++c)
        #pragma unroll
        for (int s = 0; s < 2; ++s)
            acc[c][s] = (f32x4){0.f, 0.f, 0.f, 0.f};
    #pragma unroll
    for (int c = 0; c < 4; ++c)
        #pragma unroll
        for (int kb = 0; kb < 2; ++kb) {
            int col = c * 16 + m;
            bf16x8 bh = *(const bf16x8*)&BtH[col * 72 + kb * 32 + q * 8];
            bf16x8 bl = *(const bf16x8*)&BtL[col * 72 + kb * 32 + q * 8];
            #pragma unroll
            for (int s = 0; s < 2; ++s) {
                acc[c][s] = __builtin_amdgcn_mfma_f32_16x16x32_bf16(ah[s][kb], bh, acc[c][s], 0, 0, 0);
                acc[c][s] = __builtin_amdgcn_mfma_f32_16x16x32_bf16(al[s][kb], bh, acc[c][s], 0, 0, 0);
                acc[c][s] = __builtin_amdgcn_mfma_f32_16x16x32_bf16(ah[s][kb], bl, acc[c][s], 0, 0, 0);
            }
        }

    // ---------- epilogue 1: u = tanh(P + emb), write bf16 into Us (reuses A region)
    float em[4];
    #pragma unroll
    for (int c = 0; c < 4; ++c) em[c] = emb[r * D + c * 16 + m];
    __syncthreads();   // everyone done reading Ah/Al frags
    #pragma unroll
    for (int s = 0; s < 2; ++s)
        #pragma unroll
        for (int i = 0; i < 4; ++i) {
            int row = w * 32 + s * 16 + q * 4 + i;
            #pragma unroll
            for (int c = 0; c < 4; ++c)
                Us[row * 72 + c * 16 + m] = f2bf(fast_tanh(acc[c][s][i] + em[c]));
        }
    __syncthreads();

    // ---------- GEMM2: V[row][d] = sum_o u[row][o] * W[d][o]  (B-frag = Wn rows)
    bf16x8 ua[2][2];
    #pragma unroll
    for (int s = 0; s < 2; ++s)
        #pragma unroll
        for (int kb = 0; kb < 2; ++kb) {
            int row = w * 32 + s * 16 + m;
            ua[s][kb] = *(const bf16x8*)&Us[row * 72 + kb * 32 + q * 8];
        }
    f32x4 acc2[4][2];
    #pragma unroll
    for (int c = 0; c < 4; ++c)
        #pragma unroll
        for (int s = 0; s < 2; ++s)
            acc2[c][s] = (f32x4){0.f, 0.f, 0.f, 0.f};
    #pragma unroll
    for (int c = 0; c < 4; ++c)
        #pragma unroll
        for (int kb = 0; kb < 2; ++kb) {
            int dcol = c * 16 + m;
            bf16x8 bh = *(const bf16x8*)&WnH[dcol * 72 + kb * 32 + q * 8];
            bf16x8 bl = *(const bf16x8*)&WnL[dcol * 72 + kb * 32 + q * 8];
            #pragma unroll
            for (int s = 0; s < 2; ++s) {
                acc2[c][s] = __builtin_amdgcn_mfma_f32_16x16x32_bf16(ua[s][kb], bh, acc2[c][s], 0, 0, 0);
                acc2[c][s] = __builtin_amdgcn_mfma_f32_16x16x32_bf16(ua[s][kb], bl, acc2[c][s], 0, 0, 0);
            }
        }

    // ---------- store V bf16: C/D layout col=lane&15, row=quad*4+reg
    #pragma unroll
    for (int s = 0; s < 2; ++s)
        #pragma unroll
        for (int i = 0; i < 4; ++i) {
            int row = w * 32 + s * 16 + q * 4 + i;
            int n = n0 + row;
            if (n < N) {
                size_t base = ((size_t)n * R + r) * D;
                #pragma unroll
                for (int c = 0; c < 4; ++c)
                    V[base + c * 16 + m] = f2bf(acc2[c][s][i]);
            }
        }
}

// ---------------- histogram of dst
__global__ __launch_bounds__(256) void k_hist(const int* __restrict__ dst, int* __restrict__ deg, int E) {
    int e = blockIdx.x * 256 + threadIdx.x;
    if (e < E) atomicAdd(&deg[dst[e]], 1);
}

// ---------------- scan step 1: per-1024 block inclusive scan
__global__ __launch_bounds__(1024) void k_scan1(const int* __restrict__ deg, int* __restrict__ tscan,
                                                int* __restrict__ bsum, int N) {
    __shared__ int s[1024];
    const int t = threadIdx.x;
    const int i = blockIdx.x * 1024 + t;
    int v = (i < N) ? deg[i] : 0;
    s[t] = v;
    __syncthreads();
    for (int off = 1; off < 1024; off <<= 1) {
        int tmp = (t >= off) ? s[t - off] : 0;
        __syncthreads();
        s[t] += tmp;
        __syncthreads();
    }
    if (i < N) tscan[i] = s[t];
    if (t == 1023) bsum[blockIdx.x] = s[1023];
}

// ---------------- scan step 2: parallel exclusive scan of block sums
__global__ __launch_bounds__(1024) void k_scan2(const int* __restrict__ bsum, int* __restrict__ bofs, int NB) {
    __shared__ int s[1024];
    const int t = threadIdx.x;
    int carry = 0;
    for (int b0 = 0; b0 < NB; b0 += 1024) {
        int i = b0 + t;
        int v = (i < NB) ? bsum[i] : 0;
        s[t] = v;
        __syncthreads();
        for (int off = 1; off < 1024; off <<= 1) {
            int tmp = (t >= off) ? s[t - off] : 0;
            __syncthreads();
            s[t] += tmp;
            __syncthreads();
        }
        if (i < NB) bofs[i] = carry + s[t] - v;  // exclusive
        int tot = s[1023];
        __syncthreads();
        carry += tot;
    }
}

// ---------------- scan step 3: final offsets + scatter cursor
__global__ __launch_bounds__(256) void k_scan3(const int* __restrict__ tscan, const int* __restrict__ bofs,
                                               int* __restrict__ offsets, int* __restrict__ cursor, int N) {
    int i = blockIdx.x * 256 + threadIdx.x;
    if (i <= N) {
        int v = (i == 0) ? 0 : (tscan[i - 1] + bofs[(i - 1) >> 10]);
        offsets[i] = v;
        if (i < N) cursor[i] = v;
    }
}

// ---------------- scatter edges into dst-sorted order (src | etype<<20 packed)
__global__ __launch_bounds__(256) void k_scatter(const int* __restrict__ src, const int* __restrict__ dst,
                                                 const int* __restrict__ etype, int* __restrict__ cursor,
                                                 int* __restrict__ spack, int E) {
    int e = blockIdx.x * 256 + threadIdx.x;
    if (e < E) {
        int d = dst[e];
        int p = atomicAdd(&cursor[d], 1);
        spack[p] = src[e] | (etype[e] << 20);
    }
}

// ---------------- fused att + softmax + aggregation. att = feat[src] . V[dst,et]
// One wave per dst node; V[n] (16x64 bf16 = 2KB) staged in per-wave LDS.
__global__ __launch_bounds__(256) void k_fused2(const unsigned short* __restrict__ V,
                                                const float* __restrict__ feat,
                                                const int* __restrict__ offsets,
                                                const int* __restrict__ spack,
                                                float* __restrict__ h_nb,
                                                int N, int R) {
    const int lane = threadIdx.x & 63;
    const int wav  = threadIdx.x >> 6;
    const int n = blockIdx.x * 4 + wav;
    __shared__ unsigned short vlds[4][1024];  // [wave][et*64+lane]
    if (n >= N) return;
    // stage V[n]: 512 uints, 8 iters (per-wave private region, no barrier needed)
    const unsigned int* v32 = (const unsigned int*)V;
    unsigned int* vl32 = (unsigned int*)&vlds[wav][0];
    #pragma unroll
    for (int j = 0; j < 8; ++j)
        vl32[j * 64 + lane] = v32[(size_t)n * 512 + j * 64 + lane];

    const int beg = offsets[n], end = offsets[n + 1];
    float m = -INFINITY, l = 0.f, acc = 0.f;
    for (int i = beg; i < end; ++i) {
        int pk = spack[i];
        int sv = pk & 0xFFFFF;
        int et = pk >> 20;
        float f = feat[(size_t)sv * D + lane];
        float v = bf2f(vlds[wav][et * D + lane]);
        float p = f * v;
        #pragma unroll
        for (int off = 32; off > 0; off >>= 1) p += __shfl_xor(p, off, 64);
        float att = p;
        float nm = fmaxf(m, att);
        float scale = __expf(m - nm);    // m=-inf on first edge -> 0
        float wgt   = __expf(att - nm);
        l = l * scale + wgt;
        acc = acc * scale + wgt * f;
        m = nm;
    }
    h_nb[(size_t)n * D + lane] = (end > beg) ? (acc / l) : 0.f;
}

// ---------------- final: out = lrelu((f+h)@W1^T) + lrelu((f*h)@W2^T)
__global__ __launch_bounds__(256) void k_final(const float* __restrict__ feat,
                                               const float* __restrict__ h_nb,
                                               const float* __restrict__ W1,
                                               const float* __restrict__ W2,
                                               float* __restrict__ out, int N) {
    __shared__ float W1s[64][65];
    __shared__ float W2s[64][65];
    const int t = threadIdx.x;
    for (int idx = t; idx < 64 * 64; idx += 256) {
        int row = idx >> 6, col = idx & 63;
        W1s[row][col] = W1[idx];
        W2s[row][col] = W2[idx];
    }
    __syncthreads();
    const int lane = t & 63;
    const int wav  = t >> 6;
    for (int n = blockIdx.x * 4 + wav; n < N; n += gridDim.x * 4) {
        float f = feat[(size_t)n * D + lane];
        float h = h_nb[(size_t)n * D + lane];
        float xs = f + h;
        float xp = f * h;
        float a1 = 0.f, a2 = 0.f;
        #pragma unroll
        for (int d = 0; d < 64; ++d) {
            float s1 = __shfl(xs, d, 64);
            float s2 = __shfl(xp, d, 64);
            a1 += s1 * W1s[lane][d];
            a2 += s2 * W2s[lane][d];
        }
        float o1 = (a1 > 0.f) ? a1 : 0.01f * a1;
        float o2 = (a2 > 0.f) ? a2 : 0.01f * a2;
        out[(size_t)n * D + lane] = o1 + o2;
    }
}

extern "C" void kernel_launch(void* const* d_in, const int* in_sizes, int n_in,
                              void* d_out, int out_size, void* d_ws, size_t ws_size,
                              hipStream_t stream) {
    const float* feat  = (const float*)d_in[0];
    const float* relW  = (const float*)d_in[1];
    const float* relE  = (const float*)d_in[2];
    const float* W1    = (const float*)d_in[3];
    const float* W2    = (const float*)d_in[4];
    const int*   src   = (const int*)d_in[5];
    const int*   dst   = (const int*)d_in[6];
    const int*   etype = (const int*)d_in[7];
    float* out = (float*)d_out;

    const int N = in_sizes[0] / D;
    const int R = in_sizes[2] / D;
    const int E = in_sizes[5];

    // workspace carve-up (256B aligned)
    char* w = (char*)d_ws;
    size_t off = 0;
    auto alloc = [&](size_t bytes) -> void* {
        void* p = w + off;
        off = (off + bytes + 255) & ~(size_t)255;
        return p;
    };
    unsigned short* varr = (unsigned short*)alloc((size_t)N * R * D * sizeof(unsigned short));
    float* h_nb   = (float*)alloc((size_t)N * D * sizeof(float));
    int* offsets  = (int*)alloc((size_t)(N + 1) * sizeof(int));
    int* tscan    = (int*)alloc((size_t)N * sizeof(int));
    int* cursor   = (int*)alloc((size_t)N * sizeof(int));
    int* deg      = (int*)alloc((size_t)N * sizeof(int));
    int* bsum     = (int*)alloc(2048 * sizeof(int));
    int* bofs     = (int*)alloc(2048 * sizeof(int));
    int* spack    = (int*)alloc((size_t)E * sizeof(int));
    (void)ws_size; (void)n_in; (void)out_size;

    const int NB = (N + 1023) / 1024;

    hipMemsetAsync(deg, 0, (size_t)N * sizeof(int), stream);
    k_hist<<<(E + 255) / 256, 256, 0, stream>>>(dst, deg, E);
    k_scan1<<<NB, 1024, 0, stream>>>(deg, tscan, bsum, N);
    k_scan2<<<1, 1024, 0, stream>>>(bsum, bofs, NB);
    k_scan3<<<(N + 1 + 255) / 256, 256, 0, stream>>>(tscan, bofs, offsets, cursor, N);
    k_scatter<<<(E + 255) / 256, 256, 0, stream>>>(src, dst, etype, cursor, spack, E);
    dim3 pg((N + 127) / 128, R);
    k_projv<<<pg, 256, 0, stream>>>(feat, relW, relE, varr, N, R);
    k_fused2<<<(N + 3) / 4, 256, 0, stream>>>(varr, feat, offsets, spack, h_nb, N, R);
    k_final<<<1024, 256, 0, stream>>>(feat, h_nb, W1, W2, out, N);
}

// Round 4
// 674.868 us; speedup vs baseline: 1.3562x; 1.1336x over previous
//
#include <hip/hip_runtime.h>
#include <math.h>

#define D 64

typedef __attribute__((ext_vector_type(8))) short bf16x8;
typedef __attribute__((ext_vector_type(4))) float f32x4;

static __device__ __forceinline__ unsigned short f2bf(float f) {
    unsigned int u = __float_as_uint(f);
    unsigned int r = (u + 0x7FFFu + ((u >> 16) & 1u)) >> 16;  // RNE
    return (unsigned short)r;
}
static __device__ __forceinline__ float bf2f(unsigned short h) {
    return __uint_as_float(((unsigned int)h) << 16);
}
static __device__ __forceinline__ float fast_tanh(float x) {
    x = fminf(fmaxf(x, -15.f), 15.f);
    float e = __expf(2.f * x);
    return (e - 1.f) / (e + 1.f);
}

// ---------------- pre-split W into MFMA B-fragment-ordered hi/lo bf16 arrays.
// B1 (GEMM1, P=feat@W):   element W[r][d=kb*32+q*8+j][o=c*16+m]
// B2 (GEMM2, V=u@W^T):    element W[r][d=c*16+m][o=kb*32+q*8+j]
// layout: [r][c][kb][lane=q*16+m][j]  (lane*16B contiguous -> coalesced dwordx4)
__global__ __launch_bounds__(256) void k_wsplit(const float* __restrict__ W,
                                                unsigned short* __restrict__ B1h,
                                                unsigned short* __restrict__ B1l,
                                                unsigned short* __restrict__ B2h,
                                                unsigned short* __restrict__ B2l,
                                                int R) {
    int idx = blockIdx.x * 256 + threadIdx.x;
    int per_g = R * 512;                  // 4c * 2kb * 64lane
    if (idx >= 2 * per_g) return;
    int g = idx / per_g;
    int rest = idx % per_g;
    int r = rest >> 9;
    int rest2 = rest & 511;
    int c = rest2 >> 7;
    int kb = (rest2 >> 6) & 1;
    int lane = rest2 & 63;
    int m = lane & 15, q = lane >> 4;
    bf16x8 hv, lv;
    #pragma unroll
    for (int j = 0; j < 8; ++j) {
        float v;
        if (g == 0) v = W[(size_t)r * 4096 + (kb * 32 + q * 8 + j) * 64 + (c * 16 + m)];
        else        v = W[(size_t)r * 4096 + (c * 16 + m) * 64 + (kb * 32 + q * 8 + j)];
        unsigned short h = f2bf(v);
        hv[j] = (short)h;
        lv[j] = (short)f2bf(v - bf2f(h));
    }
    size_t off = ((((size_t)r * 4 + c) * 2 + kb) * 64 + lane) * 8;
    unsigned short* ph = (g == 0) ? B1h : B2h;
    unsigned short* pl = (g == 0) ? B1l : B2l;
    *(bf16x8*)&ph[off] = hv;
    *(bf16x8*)&pl[off] = lv;
}

// ---------------- fused proj+V: per block 128 nodes, loop r inside.
// A (feat hi/lo) staged once in fragment-ordered LDS; B-frags from pre-split global.
// u = tanh(P+emb) round-trips through wave-private LDS (no barrier).
// V stored permuted: Vstore[n][r][m*4+c] = V_true[n][r][c*16+m] (8B vector stores).
__global__ __launch_bounds__(256, 3) void k_projv(const float* __restrict__ feat,
                                                  const unsigned short* __restrict__ B1h,
                                                  const unsigned short* __restrict__ B1l,
                                                  const unsigned short* __restrict__ B2h,
                                                  const unsigned short* __restrict__ B2l,
                                                  const float* __restrict__ emb,
                                                  unsigned short* __restrict__ V,
                                                  int N, int R) {
    const int n0 = blockIdx.x * 128;
    __shared__ unsigned short Ah[8192];     // 16 frags x 64 lanes x 8
    __shared__ unsigned short Al[8192];
    __shared__ unsigned short Us[4][2048];  // per-wave u frags (2s x 2kb x 64 x 8)
    const int t = threadIdx.x;

    // stage A: thread handles (row, c8): 8 consecutive d, write one 16B frag chunk
    const float4* f4 = (const float4*)feat;
    #pragma unroll
    for (int it = 0; it < 4; ++it) {
        int idx = it * 256 + t;
        int row = idx >> 3, c8 = idx & 7;
        int n = n0 + row;
        float4 v0 = make_float4(0.f, 0.f, 0.f, 0.f), v1 = v0;
        if (n < N) { v0 = f4[(size_t)n * 16 + c8 * 2]; v1 = f4[(size_t)n * 16 + c8 * 2 + 1]; }
        float vals[8] = {v0.x, v0.y, v0.z, v0.w, v1.x, v1.y, v1.z, v1.w};
        bf16x8 hv, lv;
        #pragma unroll
        for (int j = 0; j < 8; ++j) {
            unsigned short h = f2bf(vals[j]);
            hv[j] = (short)h;
            lv[j] = (short)f2bf(vals[j] - bf2f(h));
        }
        int f = (row >> 4) * 2 + (c8 >> 2);
        int ln = (c8 & 3) * 16 + (row & 15);
        *(bf16x8*)&Ah[(f * 64 + ln) * 8] = hv;
        *(bf16x8*)&Al[(f * 64 + ln) * 8] = lv;
    }
    __syncthreads();

    const int lane = t & 63, w = t >> 6;
    const int m = lane & 15, q = lane >> 4;

    // A-frags to registers once (conflict-free lane-consecutive b128)
    bf16x8 ah[2][2], al[2][2];
    #pragma unroll
    for (int s = 0; s < 2; ++s)
        #pragma unroll
        for (int kb = 0; kb < 2; ++kb) {
            int f = (w * 2 + s) * 2 + kb;
            ah[s][kb] = *(const bf16x8*)&Ah[(f * 64 + lane) * 8];
            al[s][kb] = *(const bf16x8*)&Al[(f * 64 + lane) * 8];
        }

    for (int r = 0; r < R; ++r) {
        float em[4];
        #pragma unroll
        for (int c = 0; c < 4; ++c) em[c] = emb[r * 64 + c * 16 + m];

        // ---------- GEMM1: P = feat @ W_r (3-term split)
        f32x4 acc[4][2];
        #pragma unroll
        for (int c = 0; c < 4; ++c)
            #pragma unroll
            for (int s = 0; s < 2; ++s) acc[c][s] = (f32x4){0.f, 0.f, 0.f, 0.f};
        bf16x8 cbh[2], cbl[2];
        #pragma unroll
        for (int kb = 0; kb < 2; ++kb) {
            size_t o = ((((size_t)r * 4 + 0) * 2 + kb) * 64 + lane) * 8;
            cbh[kb] = *(const bf16x8*)&B1h[o];
            cbl[kb] = *(const bf16x8*)&B1l[o];
        }
        #pragma unroll
        for (int c = 0; c < 4; ++c) {
            bf16x8 nbh[2], nbl[2];
            if (c < 3) {
                #pragma unroll
                for (int kb = 0; kb < 2; ++kb) {
                    size_t o = ((((size_t)r * 4 + c + 1) * 2 + kb) * 64 + lane) * 8;
                    nbh[kb] = *(const bf16x8*)&B1h[o];
                    nbl[kb] = *(const bf16x8*)&B1l[o];
                }
            }
            #pragma unroll
            for (int kb = 0; kb < 2; ++kb)
                #pragma unroll
                for (int s = 0; s < 2; ++s) {
                    acc[c][s] = __builtin_amdgcn_mfma_f32_16x16x32_bf16(ah[s][kb], cbh[kb], acc[c][s], 0, 0, 0);
                    acc[c][s] = __builtin_amdgcn_mfma_f32_16x16x32_bf16(al[s][kb], cbh[kb], acc[c][s], 0, 0, 0);
                    acc[c][s] = __builtin_amdgcn_mfma_f32_16x16x32_bf16(ah[s][kb], cbl[kb], acc[c][s], 0, 0, 0);
                }
            if (c < 3) {
                #pragma unroll
                for (int kb = 0; kb < 2; ++kb) { cbh[kb] = nbh[kb]; cbl[kb] = nbl[kb]; }
            }
        }

        // ---------- epilogue: u = tanh(P+emb) -> wave-private Us in A-frag layout
        #pragma unroll
        for (int s = 0; s < 2; ++s)
            #pragma unroll
            for (int c = 0; c < 4; ++c) {
                int o = c * 16 + m;
                int kb2 = o >> 5;
                int q2 = (o & 31) >> 3;
                int j = o & 7;
                #pragma unroll
                for (int i = 0; i < 4; ++i) {
                    int rr = q * 4 + i;
                    Us[w][((s * 2 + kb2) * 64 + (q2 * 16 + rr)) * 8 + j] =
                        f2bf(fast_tanh(acc[c][s][i] + em[c]));
                }
            }

        // ---------- GEMM2: V = u @ W_r^T (2-term split)
        bf16x8 ua[2][2];
        #pragma unroll
        for (int s = 0; s < 2; ++s)
            #pragma unroll
            for (int kb = 0; kb < 2; ++kb)
                ua[s][kb] = *(const bf16x8*)&Us[w][((s * 2 + kb) * 64 + lane) * 8];
        f32x4 acc2[4][2];
        #pragma unroll
        for (int c = 0; c < 4; ++c)
            #pragma unroll
            for (int s = 0; s < 2; ++s) acc2[c][s] = (f32x4){0.f, 0.f, 0.f, 0.f};
        #pragma unroll
        for (int kb = 0; kb < 2; ++kb) {
            size_t o = ((((size_t)r * 4 + 0) * 2 + kb) * 64 + lane) * 8;
            cbh[kb] = *(const bf16x8*)&B2h[o];
            cbl[kb] = *(const bf16x8*)&B2l[o];
        }
        #pragma unroll
        for (int c = 0; c < 4; ++c) {
            bf16x8 nbh[2], nbl[2];
            if (c < 3) {
                #pragma unroll
                for (int kb = 0; kb < 2; ++kb) {
                    size_t o = ((((size_t)r * 4 + c + 1) * 2 + kb) * 64 + lane) * 8;
                    nbh[kb] = *(const bf16x8*)&B2h[o];
                    nbl[kb] = *(const bf16x8*)&B2l[o];
                }
            }
            #pragma unroll
            for (int kb = 0; kb < 2; ++kb)
                #pragma unroll
                for (int s = 0; s < 2; ++s) {
                    acc2[c][s] = __builtin_amdgcn_mfma_f32_16x16x32_bf16(ua[s][kb], cbh[kb], acc2[c][s], 0, 0, 0);
                    acc2[c][s] = __builtin_amdgcn_mfma_f32_16x16x32_bf16(ua[s][kb], cbl[kb], acc2[c][s], 0, 0, 0);
                }
            if (c < 3) {
                #pragma unroll
                for (int kb = 0; kb < 2; ++kb) { cbh[kb] = nbh[kb]; cbl[kb] = nbl[kb]; }
            }
        }

        // ---------- store V permuted: Vstore[n][r][m*4+c] (8B vector per lane)
        #pragma unroll
        for (int s = 0; s < 2; ++s)
            #pragma unroll
            for (int i = 0; i < 4; ++i) {
                int n = n0 + w * 32 + s * 16 + q * 4 + i;
                if (n < N) {
                    ushort4 pv;
                    pv.x = f2bf(acc2[0][s][i]);
                    pv.y = f2bf(acc2[1][s][i]);
                    pv.z = f2bf(acc2[2][s][i]);
                    pv.w = f2bf(acc2[3][s][i]);
                    *(ushort4*)&V[((size_t)n * R + r) * 64 + m * 4] = pv;
                }
            }
    }
}

// ---------------- histogram of dst
__global__ __launch_bounds__(256) void k_hist(const int* __restrict__ dst, int* __restrict__ deg, int E) {
    int e = blockIdx.x * 256 + threadIdx.x;
    if (e < E) atomicAdd(&deg[dst[e]], 1);
}

// ---------------- scan step 1: per-1024 block inclusive scan
__global__ __launch_bounds__(1024) void k_scan1(const int* __restrict__ deg, int* __restrict__ tscan,
                                                int* __restrict__ bsum, int N) {
    __shared__ int s[1024];
    const int t = threadIdx.x;
    const int i = blockIdx.x * 1024 + t;
    int v = (i < N) ? deg[i] : 0;
    s[t] = v;
    __syncthreads();
    for (int off = 1; off < 1024; off <<= 1) {
        int tmp = (t >= off) ? s[t - off] : 0;
        __syncthreads();
        s[t] += tmp;
        __syncthreads();
    }
    if (i < N) tscan[i] = s[t];
    if (t == 1023) bsum[blockIdx.x] = s[1023];
}

// ---------------- scan step 2: parallel exclusive scan of block sums
__global__ __launch_bounds__(1024) void k_scan2(const int* __restrict__ bsum, int* __restrict__ bofs, int NB) {
    __shared__ int s[1024];
    const int t = threadIdx.x;
    int carry = 0;
    for (int b0 = 0; b0 < NB; b0 += 1024) {
        int i = b0 + t;
        int v = (i < NB) ? bsum[i] : 0;
        s[t] = v;
        __syncthreads();
        for (int off = 1; off < 1024; off <<= 1) {
            int tmp = (t >= off) ? s[t - off] : 0;
            __syncthreads();
            s[t] += tmp;
            __syncthreads();
        }
        if (i < NB) bofs[i] = carry + s[t] - v;  // exclusive
        int tot = s[1023];
        __syncthreads();
        carry += tot;
    }
}

// ---------------- scan step 3: final offsets + scatter cursor
__global__ __launch_bounds__(256) void k_scan3(const int* __restrict__ tscan, const int* __restrict__ bofs,
                                               int* __restrict__ offsets, int* __restrict__ cursor, int N) {
    int i = blockIdx.x * 256 + threadIdx.x;
    if (i <= N) {
        int v = (i == 0) ? 0 : (tscan[i - 1] + bofs[(i - 1) >> 10]);
        offsets[i] = v;
        if (i < N) cursor[i] = v;
    }
}

// ---------------- scatter edges into dst-sorted order (src | etype<<20 packed)
__global__ __launch_bounds__(256) void k_scatter(const int* __restrict__ src, const int* __restrict__ dst,
                                                 const int* __restrict__ etype, int* __restrict__ cursor,
                                                 int* __restrict__ spack, int E) {
    int e = blockIdx.x * 256 + threadIdx.x;
    if (e < E) {
        int d = dst[e];
        int p = atomicAdd(&cursor[d], 1);
        spack[p] = src[e] | (etype[e] << 20);
    }
}

// ---------------- fused att + softmax + aggregation, depth-2 pipelined gathers.
// att = feat[src] . V[dst,et]; V[n] (2KB) staged per-wave in LDS (permuted layout).
__global__ __launch_bounds__(256) void k_fused2(const unsigned short* __restrict__ V,
                                                const float* __restrict__ feat,
                                                const int* __restrict__ offsets,
                                                const int* __restrict__ spack,
                                                float* __restrict__ h_nb,
                                                int N, int R) {
    const int lane = threadIdx.x & 63;
    const int wav  = threadIdx.x >> 6;
    const int n = blockIdx.x * 4 + wav;
    __shared__ unsigned short vlds[4][1024];
    if (n >= N) return;
    const unsigned int* v32 = (const unsigned int*)V;
    unsigned int* vl32 = (unsigned int*)&vlds[wav][0];
    #pragma unroll
    for (int j = 0; j < 8; ++j)
        vl32[j * 64 + lane] = v32[(size_t)n * 512 + j * 64 + lane];

    const int beg = offsets[n], end = offsets[n + 1];
    const int vidx = ((lane & 15) << 2) + (lane >> 4);  // un-permute Vstore
    float m = -INFINITY, l = 0.f, acc = 0.f;
    if (beg < end) {
        int pk0 = spack[beg];
        int pk1 = (beg + 1 < end) ? spack[beg + 1] : pk0;
        float f0 = feat[(size_t)(pk0 & 0xFFFFF) * D + lane];
        for (int i = beg; i < end; ++i) {
            int et = pk0 >> 20;
            float f = f0;
            // prefetch i+1 gather + i+2 index
            pk0 = pk1;
            f0 = feat[(size_t)(pk0 & 0xFFFFF) * D + lane];
            pk1 = (i + 2 < end) ? spack[i + 2] : pk0;
            float v = bf2f(vlds[wav][et * D + vidx]);
            float p = f * v;
            #pragma unroll
            for (int off = 32; off > 0; off >>= 1) p += __shfl_xor(p, off, 64);
            float nm = fmaxf(m, p);
            float scale = __expf(m - nm);    // m=-inf on first edge -> 0
            float wgt   = __expf(p - nm);
            l = l * scale + wgt;
            acc = acc * scale + wgt * f;
            m = nm;
        }
    }
    h_nb[(size_t)n * D + lane] = (end > beg) ? (acc / l) : 0.f;
}

// ---------------- final: out = lrelu((f+h)@W1^T) + lrelu((f*h)@W2^T)
__global__ __launch_bounds__(256) void k_final(const float* __restrict__ feat,
                                               const float* __restrict__ h_nb,
                                               const float* __restrict__ W1,
                                               const float* __restrict__ W2,
                                               float* __restrict__ out, int N) {
    __shared__ float W1s[64][65];
    __shared__ float W2s[64][65];
    const int t = threadIdx.x;
    for (int idx = t; idx < 64 * 64; idx += 256) {
        int row = idx >> 6, col = idx & 63;
        W1s[row][col] = W1[idx];
        W2s[row][col] = W2[idx];
    }
    __syncthreads();
    const int lane = t & 63;
    const int wav  = t >> 6;
    for (int n = blockIdx.x * 4 + wav; n < N; n += gridDim.x * 4) {
        float f = feat[(size_t)n * D + lane];
        float h = h_nb[(size_t)n * D + lane];
        float xs = f + h;
        float xp = f * h;
        float a1 = 0.f, a2 = 0.f;
        #pragma unroll
        for (int d = 0; d < 64; ++d) {
            float s1 = __shfl(xs, d, 64);
            float s2 = __shfl(xp, d, 64);
            a1 += s1 * W1s[lane][d];
            a2 += s2 * W2s[lane][d];
        }
        float o1 = (a1 > 0.f) ? a1 : 0.01f * a1;
        float o2 = (a2 > 0.f) ? a2 : 0.01f * a2;
        out[(size_t)n * D + lane] = o1 + o2;
    }
}

extern "C" void kernel_launch(void* const* d_in, const int* in_sizes, int n_in,
                              void* d_out, int out_size, void* d_ws, size_t ws_size,
                              hipStream_t stream) {
    const float* feat  = (const float*)d_in[0];
    const float* relW  = (const float*)d_in[1];
    const float* relE  = (const float*)d_in[2];
    const float* W1    = (const float*)d_in[3];
    const float* W2    = (const float*)d_in[4];
    const int*   src   = (const int*)d_in[5];
    const int*   dst   = (const int*)d_in[6];
    const int*   etype = (const int*)d_in[7];
    float* out = (float*)d_out;

    const int N = in_sizes[0] / D;
    const int R = in_sizes[2] / D;
    const int E = in_sizes[5];

    // workspace carve-up (256B aligned)
    char* w = (char*)d_ws;
    size_t off = 0;
    auto alloc = [&](size_t bytes) -> void* {
        void* p = w + off;
        off = (off + bytes + 255) & ~(size_t)255;
        return p;
    };
    unsigned short* varr = (unsigned short*)alloc((size_t)N * R * D * sizeof(unsigned short));
    float* h_nb   = (float*)alloc((size_t)N * D * sizeof(float));
    int* offsets  = (int*)alloc((size_t)(N + 1) * sizeof(int));
    int* tscan    = (int*)alloc((size_t)N * sizeof(int));
    int* cursor   = (int*)alloc((size_t)N * sizeof(int));
    int* deg      = (int*)alloc((size_t)N * sizeof(int));
    int* bsum     = (int*)alloc(2048 * sizeof(int));
    int* bofs     = (int*)alloc(2048 * sizeof(int));
    int* spack    = (int*)alloc((size_t)E * sizeof(int));
    size_t wfrag = (size_t)R * 4 * 2 * 64 * 8;  // shorts per array
    unsigned short* B1h = (unsigned short*)alloc(wfrag * sizeof(unsigned short));
    unsigned short* B1l = (unsigned short*)alloc(wfrag * sizeof(unsigned short));
    unsigned short* B2h = (unsigned short*)alloc(wfrag * sizeof(unsigned short));
    unsigned short* B2l = (unsigned short*)alloc(wfrag * sizeof(unsigned short));
    (void)ws_size; (void)n_in; (void)out_size;

    const int NB = (N + 1023) / 1024;

    k_wsplit<<<(2 * R * 512 + 255) / 256, 256, 0, stream>>>(relW, B1h, B1l, B2h, B2l, R);
    hipMemsetAsync(deg, 0, (size_t)N * sizeof(int), stream);
    k_hist<<<(E + 255) / 256, 256, 0, stream>>>(dst, deg, E);
    k_scan1<<<NB, 1024, 0, stream>>>(deg, tscan, bsum, N);
    k_scan2<<<1, 1024, 0, stream>>>(bsum, bofs, NB);
    k_scan3<<<(N + 1 + 255) / 256, 256, 0, stream>>>(tscan, bofs, offsets, cursor, N);
    k_scatter<<<(E + 255) / 256, 256, 0, stream>>>(src, dst, etype, cursor, spack, E);
    k_projv<<<(N + 127) / 128, 256, 0, stream>>>(feat, B1h, B1l, B2h, B2l, relE, varr, N, R);
    k_fused2<<<(N + 3) / 4, 256, 0, stream>>>(varr, feat, offsets, spack, h_nb, N, R);
    k_final<<<1024, 256, 0, stream>>>(feat, h_nb, W1, W2, out, N);
}

// Round 5
// 666.666 us; speedup vs baseline: 1.3729x; 1.0123x over previous
//
#include <hip/hip_runtime.h>
#include <math.h>

#define D 64

typedef __attribute__((ext_vector_type(8))) short bf16x8;
typedef __attribute__((ext_vector_type(4))) float f32x4;

static __device__ __forceinline__ unsigned short f2bf(float f) {
    unsigned int u = __float_as_uint(f);
    unsigned int r = (u + 0x7FFFu + ((u >> 16) & 1u)) >> 16;  // RNE
    return (unsigned short)r;
}
static __device__ __forceinline__ float bf2f(unsigned short h) {
    return __uint_as_float(((unsigned int)h) << 16);
}

#if defined(__has_builtin)
#if __has_builtin(__builtin_amdgcn_cvt_pk_bf16_f32)
#define HAVE_PK_BF16 1
#endif
#endif

static __device__ __forceinline__ unsigned int pk2bf(float a, float b) {
#ifdef HAVE_PK_BF16
    auto v = __builtin_amdgcn_cvt_pk_bf16_f32(a, b);   // low=a, high=b
    return *(unsigned int*)&v;
#else
    return (unsigned int)f2bf(a) | ((unsigned int)f2bf(b) << 16);
#endif
}

// tanh(x) = 1 - 2/(e^{2x}+1); inf-safe at extremes (no clamp needed)
static __device__ __forceinline__ float fast_tanh(float x) {
    float e = __expf(2.f * x);
    float r = __builtin_amdgcn_rcpf(e + 1.f);
    return 1.f - 2.f * r;
}

// ---------------- pre-split W into MFMA B-fragment-ordered hi/lo bf16 arrays.
// B1 (GEMM1, P=feat@W):   element W[r][d=kb*32+q*8+j][o=c*16+m]
// B2 (GEMM2, V=u@W^T):    element W[r][d=c*16+m][o=kb*32+q*8+j]
// layout: [r][c][kb][lane=q*16+m][j]
__global__ __launch_bounds__(256) void k_wsplit(const float* __restrict__ W,
                                                unsigned short* __restrict__ B1h,
                                                unsigned short* __restrict__ B1l,
                                                unsigned short* __restrict__ B2h,
                                                unsigned short* __restrict__ B2l,
                                                int R) {
    int idx = blockIdx.x * 256 + threadIdx.x;
    int per_g = R * 512;
    if (idx >= 2 * per_g) return;
    int g = idx / per_g;
    int rest = idx % per_g;
    int r = rest >> 9;
    int rest2 = rest & 511;
    int c = rest2 >> 7;
    int kb = (rest2 >> 6) & 1;
    int lane = rest2 & 63;
    int m = lane & 15, q = lane >> 4;
    bf16x8 hv, lv;
    #pragma unroll
    for (int j = 0; j < 8; ++j) {
        float v;
        if (g == 0) v = W[(size_t)r * 4096 + (kb * 32 + q * 8 + j) * 64 + (c * 16 + m)];
        else        v = W[(size_t)r * 4096 + (c * 16 + m) * 64 + (kb * 32 + q * 8 + j)];
        unsigned short h = f2bf(v);
        hv[j] = (short)h;
        lv[j] = (short)f2bf(v - bf2f(h));
    }
    size_t off = ((((size_t)r * 4 + c) * 2 + kb) * 64 + lane) * 8;
    unsigned short* ph = (g == 0) ? B1h : B2h;
    unsigned short* pl = (g == 0) ? B1l : B2l;
    *(bf16x8*)&ph[off] = hv;
    *(bf16x8*)&pl[off] = lv;
}

// ---------------- fused proj+V, latency-pipelined. 128 nodes/block, r-loop inside.
// A-frags loaded straight from global (no A LDS, no barriers). B-frag loads are
// software-pipelined across GEMM phases. Us (tanh round-trip) is wave-private,
// XOR-swizzled LDS. V stored permuted: Vstore[n][r][m*4+c] = V_true[n][r][c*16+m].
__global__ __launch_bounds__(256, 3) void k_projv(const float* __restrict__ feat,
                                                  const unsigned short* __restrict__ B1h,
                                                  const unsigned short* __restrict__ B1l,
                                                  const unsigned short* __restrict__ B2h,
                                                  const unsigned short* __restrict__ B2l,
                                                  const float* __restrict__ emb,
                                                  unsigned short* __restrict__ V,
                                                  int N, int R) {
    const int n0 = blockIdx.x * 128;
    __shared__ unsigned short Us[4][2048];   // per-wave 32rows x 64o, frag-ordered+swizzled
    const int t = threadIdx.x;
    const int lane = t & 63, w = t >> 6;
    const int m = lane & 15, q = lane >> 4;

    // ---- A-frags direct from global, split hi/lo in-register
    bf16x8 ah[2][2], al[2][2];
    #pragma unroll
    for (int s = 0; s < 2; ++s) {
        int n = n0 + w * 32 + s * 16 + m;
        const float* rowp = feat + (size_t)n * D;
        #pragma unroll
        for (int kb = 0; kb < 2; ++kb) {
            int d0 = kb * 32 + q * 8;
            float4 v0 = make_float4(0.f, 0.f, 0.f, 0.f), v1 = v0;
            if (n < N) { v0 = *(const float4*)(rowp + d0); v1 = *(const float4*)(rowp + d0 + 4); }
            float vals[8] = {v0.x, v0.y, v0.z, v0.w, v1.x, v1.y, v1.z, v1.w};
            bf16x8 hv, lv;
            #pragma unroll
            for (int j = 0; j < 8; ++j) {
                unsigned short h = f2bf(vals[j]);
                hv[j] = (short)h;
                lv[j] = (short)f2bf(vals[j] - bf2f(h));
            }
            ah[s][kb] = hv; al[s][kb] = lv;
        }
    }

    struct Slice { bf16x8 h[2]; bf16x8 l[2]; };
    auto loadS = [&](const unsigned short* H, const unsigned short* L, int r, int c) {
        Slice sl;
        size_t base = ((size_t)r * 8 + c * 2) * 512 + (size_t)lane * 8;
        sl.h[0] = *(const bf16x8*)&H[base];
        sl.h[1] = *(const bf16x8*)&H[base + 512];
        sl.l[0] = *(const bf16x8*)&L[base];
        sl.l[1] = *(const bf16x8*)&L[base + 512];
        return sl;
    };

    Slice b1a = loadS(B1h, B1l, 0, 0);   // prologue: B1(r=0, c0/c1)
    Slice b1b = loadS(B1h, B1l, 0, 1);

    for (int r = 0; r < R; ++r) {
        float em[4];
        #pragma unroll
        for (int c = 0; c < 4; ++c) em[c] = emb[r * 64 + c * 16 + m];

        f32x4 acc[4][2];
        #pragma unroll
        for (int c = 0; c < 4; ++c)
            #pragma unroll
            for (int s = 0; s < 2; ++s) acc[c][s] = (f32x4){0.f, 0.f, 0.f, 0.f};

        auto G1 = [&](int c, const Slice& S) {
            #pragma unroll
            for (int kb = 0; kb < 2; ++kb)
                #pragma unroll
                for (int s = 0; s < 2; ++s) {
                    acc[c][s] = __builtin_amdgcn_mfma_f32_16x16x32_bf16(ah[s][kb], S.h[kb], acc[c][s], 0, 0, 0);
                    acc[c][s] = __builtin_amdgcn_mfma_f32_16x16x32_bf16(al[s][kb], S.h[kb], acc[c][s], 0, 0, 0);
                    acc[c][s] = __builtin_amdgcn_mfma_f32_16x16x32_bf16(ah[s][kb], S.l[kb], acc[c][s], 0, 0, 0);
                }
        };

        // ---- GEMM1, pipelined: prefetch c2,c3 then B2 c0,c1
        Slice c2 = loadS(B1h, B1l, r, 2);
        G1(0, b1a);
        Slice c3 = loadS(B1h, B1l, r, 3);
        G1(1, b1b);
        Slice b2a = loadS(B2h, B2l, r, 0);
        G1(2, c2);
        Slice b2b = loadS(B2h, B2l, r, 1);
        G1(3, c3);

        // ---- epilogue 1: u = tanh(P+emb) -> swizzled wave-private Us (hides b2a/b2b)
        #pragma unroll
        for (int s = 0; s < 2; ++s)
            #pragma unroll
            for (int c = 0; c < 4; ++c) {
                int o = c * 16 + m;
                int kb2 = o >> 5;
                int q2 = (o >> 3) & 3;
                int j = o & 7;
                int Fb = (s * 2 + kb2) * 64 + q2 * 16 + q * 4;
                #pragma unroll
                for (int i = 0; i < 4; i += 2) {
                    float t0 = fast_tanh(acc[c][s][i] + em[c]);
                    float t1 = fast_tanh(acc[c][s][i + 1] + em[c]);
                    unsigned int pk = pk2bf(t0, t1);
                    Us[w][((Fb + i) ^ q2) * 8 + j]     = (unsigned short)(pk & 0xFFFF);
                    Us[w][((Fb + i + 1) ^ q2) * 8 + j] = (unsigned short)(pk >> 16);
                }
            }

        // ---- GEMM2, pipelined; tail prefetches B1(r+1, c0/c1) for next iteration
        Slice d2 = loadS(B2h, B2l, r, 2);
        bf16x8 ua[2][2];
        #pragma unroll
        for (int s = 0; s < 2; ++s)
            #pragma unroll
            for (int kb = 0; kb < 2; ++kb) {
                int F = (s * 2 + kb) * 64 + lane;
                ua[s][kb] = *(const bf16x8*)&Us[w][(F ^ (lane >> 4)) * 8];
            }
        f32x4 acc2[4][2];
        #pragma unroll
        for (int c = 0; c < 4; ++c)
            #pragma unroll
            for (int s = 0; s < 2; ++s) acc2[c][s] = (f32x4){0.f, 0.f, 0.f, 0.f};

        auto G2 = [&](int c, const Slice& S) {
            #pragma unroll
            for (int kb = 0; kb < 2; ++kb)
                #pragma unroll
                for (int s = 0; s < 2; ++s) {
                    acc2[c][s] = __builtin_amdgcn_mfma_f32_16x16x32_bf16(ua[s][kb], S.h[kb], acc2[c][s], 0, 0, 0);
                    acc2[c][s] = __builtin_amdgcn_mfma_f32_16x16x32_bf16(ua[s][kb], S.l[kb], acc2[c][s], 0, 0, 0);
                }
        };

        int rn = (r + 1 < R) ? r + 1 : 0;
        G2(0, b2a);
        Slice d3 = loadS(B2h, B2l, r, 3);
        G2(1, b2b);
        b1a = loadS(B1h, B1l, rn, 0);
        G2(2, d2);
        b1b = loadS(B1h, B1l, rn, 1);
        G2(3, d3);

        // ---- epilogue 2: store V permuted (hides b1a/b1b for next r)
        #pragma unroll
        for (int s = 0; s < 2; ++s)
            #pragma unroll
            for (int i = 0; i < 4; ++i) {
                int n = n0 + w * 32 + s * 16 + q * 4 + i;
                if (n < N) {
                    uint2 pv;
                    pv.x = pk2bf(acc2[0][s][i], acc2[1][s][i]);
                    pv.y = pk2bf(acc2[2][s][i], acc2[3][s][i]);
                    *(uint2*)&V[((size_t)n * R + r) * 64 + m * 4] = pv;
                }
            }
    }
}

// ---------------- histogram of dst
__global__ __launch_bounds__(256) void k_hist(const int* __restrict__ dst, int* __restrict__ deg, int E) {
    int e = blockIdx.x * 256 + threadIdx.x;
    if (e < E) atomicAdd(&deg[dst[e]], 1);
}

// ---------------- scan step 1: per-1024 block inclusive scan
__global__ __launch_bounds__(1024) void k_scan1(const int* __restrict__ deg, int* __restrict__ tscan,
                                                int* __restrict__ bsum, int N) {
    __shared__ int s[1024];
    const int t = threadIdx.x;
    const int i = blockIdx.x * 1024 + t;
    int v = (i < N) ? deg[i] : 0;
    s[t] = v;
    __syncthreads();
    for (int off = 1; off < 1024; off <<= 1) {
        int tmp = (t >= off) ? s[t - off] : 0;
        __syncthreads();
        s[t] += tmp;
        __syncthreads();
    }
    if (i < N) tscan[i] = s[t];
    if (t == 1023) bsum[blockIdx.x] = s[1023];
}

// ---------------- scan step 2: parallel exclusive scan of block sums
__global__ __launch_bounds__(1024) void k_scan2(const int* __restrict__ bsum, int* __restrict__ bofs, int NB) {
    __shared__ int s[1024];
    const int t = threadIdx.x;
    int carry = 0;
    for (int b0 = 0; b0 < NB; b0 += 1024) {
        int i = b0 + t;
        int v = (i < NB) ? bsum[i] : 0;
        s[t] = v;
        __syncthreads();
        for (int off = 1; off < 1024; off <<= 1) {
            int tmp = (t >= off) ? s[t - off] : 0;
            __syncthreads();
            s[t] += tmp;
            __syncthreads();
        }
        if (i < NB) bofs[i] = carry + s[t] - v;  // exclusive
        int tot = s[1023];
        __syncthreads();
        carry += tot;
    }
}

// ---------------- scan step 3: final offsets + scatter cursor
__global__ __launch_bounds__(256) void k_scan3(const int* __restrict__ tscan, const int* __restrict__ bofs,
                                               int* __restrict__ offsets, int* __restrict__ cursor, int N) {
    int i = blockIdx.x * 256 + threadIdx.x;
    if (i <= N) {
        int v = (i == 0) ? 0 : (tscan[i - 1] + bofs[(i - 1) >> 10]);
        offsets[i] = v;
        if (i < N) cursor[i] = v;
    }
}

// ---------------- scatter edges into dst-sorted order (src | etype<<20 packed)
__global__ __launch_bounds__(256) void k_scatter(const int* __restrict__ src, const int* __restrict__ dst,
                                                 const int* __restrict__ etype, int* __restrict__ cursor,
                                                 int* __restrict__ spack, int E) {
    int e = blockIdx.x * 256 + threadIdx.x;
    if (e < E) {
        int d = dst[e];
        int p = atomicAdd(&cursor[d], 1);
        spack[p] = src[e] | (etype[e] << 20);
    }
}

// ---------------- fused att + softmax + aggregation, depth-2 pipelined gathers.
__global__ __launch_bounds__(256) void k_fused2(const unsigned short* __restrict__ V,
                                                const float* __restrict__ feat,
                                                const int* __restrict__ offsets,
                                                const int* __restrict__ spack,
                                                float* __restrict__ h_nb,
                                                int N, int R) {
    const int lane = threadIdx.x & 63;
    const int wav  = threadIdx.x >> 6;
    const int n = blockIdx.x * 4 + wav;
    __shared__ unsigned short vlds[4][1024];
    if (n >= N) return;
    const unsigned int* v32 = (const unsigned int*)V;
    unsigned int* vl32 = (unsigned int*)&vlds[wav][0];
    #pragma unroll
    for (int j = 0; j < 8; ++j)
        vl32[j * 64 + lane] = v32[(size_t)n * 512 + j * 64 + lane];

    const int beg = offsets[n], end = offsets[n + 1];
    const int vidx = ((lane & 15) << 2) + (lane >> 4);  // un-permute Vstore
    float m = -INFINITY, l = 0.f, acc = 0.f;
    if (beg < end) {
        int pk0 = spack[beg];
        int pk1 = (beg + 1 < end) ? spack[beg + 1] : pk0;
        float f0 = feat[(size_t)(pk0 & 0xFFFFF) * D + lane];
        for (int i = beg; i < end; ++i) {
            int et = pk0 >> 20;
            float f = f0;
            pk0 = pk1;
            f0 = feat[(size_t)(pk0 & 0xFFFFF) * D + lane];
            pk1 = (i + 2 < end) ? spack[i + 2] : pk0;
            float v = bf2f(vlds[wav][et * D + vidx]);
            float p = f * v;
            #pragma unroll
            for (int off = 32; off > 0; off >>= 1) p += __shfl_xor(p, off, 64);
            float nm = fmaxf(m, p);
            float scale = __expf(m - nm);    // m=-inf on first edge -> 0
            float wgt   = __expf(p - nm);
            l = l * scale + wgt;
            acc = acc * scale + wgt * f;
            m = nm;
        }
    }
    h_nb[(size_t)n * D + lane] = (end > beg) ? (acc / l) : 0.f;
}

// ---------------- final: out = lrelu((f+h)@W1^T) + lrelu((f*h)@W2^T)
__global__ __launch_bounds__(256) void k_final(const float* __restrict__ feat,
                                               const float* __restrict__ h_nb,
                                               const float* __restrict__ W1,
                                               const float* __restrict__ W2,
                                               float* __restrict__ out, int N) {
    __shared__ float W1s[64][65];
    __shared__ float W2s[64][65];
    const int t = threadIdx.x;
    for (int idx = t; idx < 64 * 64; idx += 256) {
        int row = idx >> 6, col = idx & 63;
        W1s[row][col] = W1[idx];
        W2s[row][col] = W2[idx];
    }
    __syncthreads();
    const int lane = t & 63;
    const int wav  = t >> 6;
    for (int n = blockIdx.x * 4 + wav; n < N; n += gridDim.x * 4) {
        float f = feat[(size_t)n * D + lane];
        float h = h_nb[(size_t)n * D + lane];
        float xs = f + h;
        float xp = f * h;
        float a1 = 0.f, a2 = 0.f;
        #pragma unroll
        for (int d = 0; d < 64; ++d) {
            float s1 = __shfl(xs, d, 64);
            float s2 = __shfl(xp, d, 64);
            a1 += s1 * W1s[lane][d];
            a2 += s2 * W2s[lane][d];
        }
        float o1 = (a1 > 0.f) ? a1 : 0.01f * a1;
        float o2 = (a2 > 0.f) ? a2 : 0.01f * a2;
        out[(size_t)n * D + lane] = o1 + o2;
    }
}

extern "C" void kernel_launch(void* const* d_in, const int* in_sizes, int n_in,
                              void* d_out, int out_size, void* d_ws, size_t ws_size,
                              hipStream_t stream) {
    const float* feat  = (const float*)d_in[0];
    const float* relW  = (const float*)d_in[1];
    const float* relE  = (const float*)d_in[2];
    const float* W1    = (const float*)d_in[3];
    const float* W2    = (const float*)d_in[4];
    const int*   src   = (const int*)d_in[5];
    const int*   dst   = (const int*)d_in[6];
    const int*   etype = (const int*)d_in[7];
    float* out = (float*)d_out;

    const int N = in_sizes[0] / D;
    const int R = in_sizes[2] / D;
    const int E = in_sizes[5];

    char* w = (char*)d_ws;
    size_t off = 0;
    auto alloc = [&](size_t bytes) -> void* {
        void* p = w + off;
        off = (off + bytes + 255) & ~(size_t)255;
        return p;
    };
    unsigned short* varr = (unsigned short*)alloc((size_t)N * R * D * sizeof(unsigned short));
    float* h_nb   = (float*)alloc((size_t)N * D * sizeof(float));
    int* offsets  = (int*)alloc((size_t)(N + 1) * sizeof(int));
    int* tscan    = (int*)alloc((size_t)N * sizeof(int));
    int* cursor   = (int*)alloc((size_t)N * sizeof(int));
    int* deg      = (int*)alloc((size_t)N * sizeof(int));
    int* bsum     = (int*)alloc(2048 * sizeof(int));
    int* bofs     = (int*)alloc(2048 * sizeof(int));
    int* spack    = (int*)alloc((size_t)E * sizeof(int));
    size_t wfrag = (size_t)R * 4 * 2 * 64 * 8;
    unsigned short* B1h = (unsigned short*)alloc(wfrag * sizeof(unsigned short));
    unsigned short* B1l = (unsigned short*)alloc(wfrag * sizeof(unsigned short));
    unsigned short* B2h = (unsigned short*)alloc(wfrag * sizeof(unsigned short));
    unsigned short* B2l = (unsigned short*)alloc(wfrag * sizeof(unsigned short));
    (void)ws_size; (void)n_in; (void)out_size;

    const int NB = (N + 1023) / 1024;

    k_wsplit<<<(2 * R * 512 + 255) / 256, 256, 0, stream>>>(relW, B1h, B1l, B2h, B2l, R);
    hipMemsetAsync(deg, 0, (size_t)N * sizeof(int), stream);
    k_hist<<<(E + 255) / 256, 256, 0, stream>>>(dst, deg, E);
    k_scan1<<<NB, 1024, 0, stream>>>(deg, tscan, bsum, N);
    k_scan2<<<1, 1024, 0, stream>>>(bsum, bofs, NB);
    k_scan3<<<(N + 1 + 255) / 256, 256, 0, stream>>>(tscan, bofs, offsets, cursor, N);
    k_scatter<<<(E + 255) / 256, 256, 0, stream>>>(src, dst, etype, cursor, spack, E);
    k_projv<<<(N + 127) / 128, 256, 0, stream>>>(feat, B1h, B1l, B2h, B2l, relE, varr, N, R);
    k_fused2<<<(N + 3) / 4, 256, 0, stream>>>(varr, feat, offsets, spack, h_nb, N, R);
    k_final<<<1024, 256, 0, stream>>>(feat, h_nb, W1, W2, out, N);
}

// Round 6
// 619.564 us; speedup vs baseline: 1.4773x; 1.0760x over previous
//
#include <hip/hip_runtime.h>
#include <math.h>

#define D 64

typedef __attribute__((ext_vector_type(8))) short bf16x8;
typedef __attribute__((ext_vector_type(4))) float f32x4;

static __device__ __forceinline__ unsigned short f2bf(float f) {
    unsigned int u = __float_as_uint(f);
    unsigned int r = (u + 0x7FFFu + ((u >> 16) & 1u)) >> 16;  // RNE
    return (unsigned short)r;
}
static __device__ __forceinline__ float bf2f(unsigned short h) {
    return __uint_as_float(((unsigned int)h) << 16);
}

#if defined(__has_builtin)
#if __has_builtin(__builtin_amdgcn_cvt_pk_bf16_f32)
#define HAVE_PK_BF16 1
#endif
#endif

static __device__ __forceinline__ unsigned int pk2bf(float a, float b) {
#ifdef HAVE_PK_BF16
    auto v = __builtin_amdgcn_cvt_pk_bf16_f32(a, b);   // low=a, high=b
    return *(unsigned int*)&v;
#else
    return (unsigned int)f2bf(a) | ((unsigned int)f2bf(b) << 16);
#endif
}

// tanh(x) = 1 - 2/(e^{2x}+1); inf-safe at extremes (no clamp needed)
static __device__ __forceinline__ float fast_tanh(float x) {
    float e = __expf(2.f * x);
    float r = __builtin_amdgcn_rcpf(e + 1.f);
    return 1.f - 2.f * r;
}

// ---------------- pre-split W into MFMA B-fragment-ordered hi/lo bf16 arrays.
__global__ __launch_bounds__(256) void k_wsplit(const float* __restrict__ W,
                                                unsigned short* __restrict__ B1h,
                                                unsigned short* __restrict__ B1l,
                                                unsigned short* __restrict__ B2h,
                                                unsigned short* __restrict__ B2l,
                                                int R) {
    int idx = blockIdx.x * 256 + threadIdx.x;
    int per_g = R * 512;
    if (idx >= 2 * per_g) return;
    int g = idx / per_g;
    int rest = idx % per_g;
    int r = rest >> 9;
    int rest2 = rest & 511;
    int c = rest2 >> 7;
    int kb = (rest2 >> 6) & 1;
    int lane = rest2 & 63;
    int m = lane & 15, q = lane >> 4;
    bf16x8 hv, lv;
    #pragma unroll
    for (int j = 0; j < 8; ++j) {
        float v;
        if (g == 0) v = W[(size_t)r * 4096 + (kb * 32 + q * 8 + j) * 64 + (c * 16 + m)];
        else        v = W[(size_t)r * 4096 + (c * 16 + m) * 64 + (kb * 32 + q * 8 + j)];
        unsigned short h = f2bf(v);
        hv[j] = (short)h;
        lv[j] = (short)f2bf(v - bf2f(h));
    }
    size_t off = ((((size_t)r * 4 + c) * 2 + kb) * 64 + lane) * 8;
    unsigned short* ph = (g == 0) ? B1h : B2h;
    unsigned short* pl = (g == 0) ? B1l : B2l;
    *(bf16x8*)&ph[off] = hv;
    *(bf16x8*)&pl[off] = lv;
}

// ---------------- fused proj+V, latency-pipelined (unchanged from R5).
__global__ __launch_bounds__(256, 3) void k_projv(const float* __restrict__ feat,
                                                  const unsigned short* __restrict__ B1h,
                                                  const unsigned short* __restrict__ B1l,
                                                  const unsigned short* __restrict__ B2h,
                                                  const unsigned short* __restrict__ B2l,
                                                  const float* __restrict__ emb,
                                                  unsigned short* __restrict__ V,
                                                  int N, int R) {
    const int n0 = blockIdx.x * 128;
    __shared__ unsigned short Us[4][2048];
    const int t = threadIdx.x;
    const int lane = t & 63, w = t >> 6;
    const int m = lane & 15, q = lane >> 4;

    bf16x8 ah[2][2], al[2][2];
    #pragma unroll
    for (int s = 0; s < 2; ++s) {
        int n = n0 + w * 32 + s * 16 + m;
        const float* rowp = feat + (size_t)n * D;
        #pragma unroll
        for (int kb = 0; kb < 2; ++kb) {
            int d0 = kb * 32 + q * 8;
            float4 v0 = make_float4(0.f, 0.f, 0.f, 0.f), v1 = v0;
            if (n < N) { v0 = *(const float4*)(rowp + d0); v1 = *(const float4*)(rowp + d0 + 4); }
            float vals[8] = {v0.x, v0.y, v0.z, v0.w, v1.x, v1.y, v1.z, v1.w};
            bf16x8 hv, lv;
            #pragma unroll
            for (int j = 0; j < 8; ++j) {
                unsigned short h = f2bf(vals[j]);
                hv[j] = (short)h;
                lv[j] = (short)f2bf(vals[j] - bf2f(h));
            }
            ah[s][kb] = hv; al[s][kb] = lv;
        }
    }

    struct Slice { bf16x8 h[2]; bf16x8 l[2]; };
    auto loadS = [&](const unsigned short* H, const unsigned short* L, int r, int c) {
        Slice sl;
        size_t base = ((size_t)r * 8 + c * 2) * 512 + (size_t)lane * 8;
        sl.h[0] = *(const bf16x8*)&H[base];
        sl.h[1] = *(const bf16x8*)&H[base + 512];
        sl.l[0] = *(const bf16x8*)&L[base];
        sl.l[1] = *(const bf16x8*)&L[base + 512];
        return sl;
    };

    Slice b1a = loadS(B1h, B1l, 0, 0);
    Slice b1b = loadS(B1h, B1l, 0, 1);

    for (int r = 0; r < R; ++r) {
        float em[4];
        #pragma unroll
        for (int c = 0; c < 4; ++c) em[c] = emb[r * 64 + c * 16 + m];

        f32x4 acc[4][2];
        #pragma unroll
        for (int c = 0; c < 4; ++c)
            #pragma unroll
            for (int s = 0; s < 2; ++s) acc[c][s] = (f32x4){0.f, 0.f, 0.f, 0.f};

        auto G1 = [&](int c, const Slice& S) {
            #pragma unroll
            for (int kb = 0; kb < 2; ++kb)
                #pragma unroll
                for (int s = 0; s < 2; ++s) {
                    acc[c][s] = __builtin_amdgcn_mfma_f32_16x16x32_bf16(ah[s][kb], S.h[kb], acc[c][s], 0, 0, 0);
                    acc[c][s] = __builtin_amdgcn_mfma_f32_16x16x32_bf16(al[s][kb], S.h[kb], acc[c][s], 0, 0, 0);
                    acc[c][s] = __builtin_amdgcn_mfma_f32_16x16x32_bf16(ah[s][kb], S.l[kb], acc[c][s], 0, 0, 0);
                }
        };

        Slice c2 = loadS(B1h, B1l, r, 2);
        G1(0, b1a);
        Slice c3 = loadS(B1h, B1l, r, 3);
        G1(1, b1b);
        Slice b2a = loadS(B2h, B2l, r, 0);
        G1(2, c2);
        Slice b2b = loadS(B2h, B2l, r, 1);
        G1(3, c3);

        #pragma unroll
        for (int s = 0; s < 2; ++s)
            #pragma unroll
            for (int c = 0; c < 4; ++c) {
                int o = c * 16 + m;
                int kb2 = o >> 5;
                int q2 = (o >> 3) & 3;
                int j = o & 7;
                int Fb = (s * 2 + kb2) * 64 + q2 * 16 + q * 4;
                #pragma unroll
                for (int i = 0; i < 4; i += 2) {
                    float t0 = fast_tanh(acc[c][s][i] + em[c]);
                    float t1 = fast_tanh(acc[c][s][i + 1] + em[c]);
                    unsigned int pk = pk2bf(t0, t1);
                    Us[w][((Fb + i) ^ q2) * 8 + j]     = (unsigned short)(pk & 0xFFFF);
                    Us[w][((Fb + i + 1) ^ q2) * 8 + j] = (unsigned short)(pk >> 16);
                }
            }

        Slice d2 = loadS(B2h, B2l, r, 2);
        bf16x8 ua[2][2];
        #pragma unroll
        for (int s = 0; s < 2; ++s)
            #pragma unroll
            for (int kb = 0; kb < 2; ++kb) {
                int F = (s * 2 + kb) * 64 + lane;
                ua[s][kb] = *(const bf16x8*)&Us[w][(F ^ (lane >> 4)) * 8];
            }
        f32x4 acc2[4][2];
        #pragma unroll
        for (int c = 0; c < 4; ++c)
            #pragma unroll
            for (int s = 0; s < 2; ++s) acc2[c][s] = (f32x4){0.f, 0.f, 0.f, 0.f};

        auto G2 = [&](int c, const Slice& S) {
            #pragma unroll
            for (int kb = 0; kb < 2; ++kb)
                #pragma unroll
                for (int s = 0; s < 2; ++s) {
                    acc2[c][s] = __builtin_amdgcn_mfma_f32_16x16x32_bf16(ua[s][kb], S.h[kb], acc2[c][s], 0, 0, 0);
                    acc2[c][s] = __builtin_amdgcn_mfma_f32_16x16x32_bf16(ua[s][kb], S.l[kb], acc2[c][s], 0, 0, 0);
                }
        };

        int rn = (r + 1 < R) ? r + 1 : 0;
        G2(0, b2a);
        Slice d3 = loadS(B2h, B2l, r, 3);
        G2(1, b2b);
        b1a = loadS(B1h, B1l, rn, 0);
        G2(2, d2);
        b1b = loadS(B1h, B1l, rn, 1);
        G2(3, d3);

        #pragma unroll
        for (int s = 0; s < 2; ++s)
            #pragma unroll
            for (int i = 0; i < 4; ++i) {
                int n = n0 + w * 32 + s * 16 + q * 4 + i;
                if (n < N) {
                    uint2 pv;
                    pv.x = pk2bf(acc2[0][s][i], acc2[1][s][i]);
                    pv.y = pk2bf(acc2[2][s][i], acc2[3][s][i]);
                    *(uint2*)&V[((size_t)n * R + r) * 64 + m * 4] = pv;
                }
            }
    }
}

// ---------------- histogram of dst
__global__ __launch_bounds__(256) void k_hist(const int* __restrict__ dst, int* __restrict__ deg, int E) {
    int e = blockIdx.x * 256 + threadIdx.x;
    if (e < E) atomicAdd(&deg[dst[e]], 1);
}

// ---------------- scan step 1
__global__ __launch_bounds__(1024) void k_scan1(const int* __restrict__ deg, int* __restrict__ tscan,
                                                int* __restrict__ bsum, int N) {
    __shared__ int s[1024];
    const int t = threadIdx.x;
    const int i = blockIdx.x * 1024 + t;
    int v = (i < N) ? deg[i] : 0;
    s[t] = v;
    __syncthreads();
    for (int off = 1; off < 1024; off <<= 1) {
        int tmp = (t >= off) ? s[t - off] : 0;
        __syncthreads();
        s[t] += tmp;
        __syncthreads();
    }
    if (i < N) tscan[i] = s[t];
    if (t == 1023) bsum[blockIdx.x] = s[1023];
}

// ---------------- scan step 2
__global__ __launch_bounds__(1024) void k_scan2(const int* __restrict__ bsum, int* __restrict__ bofs, int NB) {
    __shared__ int s[1024];
    const int t = threadIdx.x;
    int carry = 0;
    for (int b0 = 0; b0 < NB; b0 += 1024) {
        int i = b0 + t;
        int v = (i < NB) ? bsum[i] : 0;
        s[t] = v;
        __syncthreads();
        for (int off = 1; off < 1024; off <<= 1) {
            int tmp = (t >= off) ? s[t - off] : 0;
            __syncthreads();
            s[t] += tmp;
            __syncthreads();
        }
        if (i < NB) bofs[i] = carry + s[t] - v;
        int tot = s[1023];
        __syncthreads();
        carry += tot;
    }
}

// ---------------- scan step 3
__global__ __launch_bounds__(256) void k_scan3(const int* __restrict__ tscan, const int* __restrict__ bofs,
                                               int* __restrict__ offsets, int* __restrict__ cursor, int N) {
    int i = blockIdx.x * 256 + threadIdx.x;
    if (i <= N) {
        int v = (i == 0) ? 0 : (tscan[i - 1] + bofs[(i - 1) >> 10]);
        offsets[i] = v;
        if (i < N) cursor[i] = v;
    }
}

// ---------------- scatter edges into dst-sorted order
__global__ __launch_bounds__(256) void k_scatter(const int* __restrict__ src, const int* __restrict__ dst,
                                                 const int* __restrict__ etype, int* __restrict__ cursor,
                                                 int* __restrict__ spack, int E) {
    int e = blockIdx.x * 256 + threadIdx.x;
    if (e < E) {
        int d = dst[e];
        int p = atomicAdd(&cursor[d], 1);
        spack[p] = src[e] | (etype[e] << 20);
    }
}

// ---------------- fused att + softmax + aggregation: 4 edges per wave-iteration.
// Wave = 4 groups x 16 lanes; group g handles edge i+g; lane holds dims 4k..4k+3.
__global__ __launch_bounds__(256) void k_fused2(const unsigned short* __restrict__ V,
                                                const float* __restrict__ feat,
                                                const int* __restrict__ offsets,
                                                const int* __restrict__ spack,
                                                float* __restrict__ h_nb,
                                                int N, int R) {
    const int lane = threadIdx.x & 63;
    const int wav  = threadIdx.x >> 6;
    const int g    = lane >> 4;     // edge-group 0..3
    const int k    = lane & 15;     // lane-in-group (dims 4k..4k+3)
    const int n = blockIdx.x * 4 + wav;
    __shared__ float vlds[4][1024];   // [wave][r*64 + dim], natural order, fp32
    if (n >= N) return;

    // stage V[n]: read permuted bf16 pairs, un-permute to natural fp32
    const unsigned int* v32 = (const unsigned int*)(V + (size_t)n * R * D);
    #pragma unroll
    for (int j = 0; j < 8; ++j) {
        int uidx = j * 64 + lane;
        unsigned int u = v32[uidx];
        int r  = uidx >> 5;
        int k2 = uidx & 31;
        int mm = k2 >> 1;
        int cc = (k2 & 1) * 2;
        int o  = cc * 16 + mm;
        vlds[wav][r * 64 + o]      = bf2f((unsigned short)(u & 0xFFFF));
        vlds[wav][r * 64 + o + 16] = bf2f((unsigned short)(u >> 16));
    }

    const int beg = offsets[n], end = offsets[n + 1];
    float m = -INFINITY, l = 0.f;
    float4 acc = make_float4(0.f, 0.f, 0.f, 0.f);

    if (beg < end) {
        // prefetch edge beg+g
        int e = beg + g;
        bool ok = e < end;
        int pk = spack[ok ? e : (end - 1)];
        float4 f = *(const float4*)&feat[(size_t)(pk & 0xFFFFF) * D + k * 4];

        for (int i = beg; i < end; i += 4) {
            const int   et  = pk >> 20;
            const float4 fc = f;
            const bool  okc = ok;
            // prefetch next 4-edge batch
            int e2 = i + 4 + g;
            ok = e2 < end;
            pk = spack[ok ? e2 : (end - 1)];
            f = *(const float4*)&feat[(size_t)(pk & 0xFFFFF) * D + k * 4];

            float4 v = *(const float4*)&vlds[wav][et * 64 + k * 4];
            float p = fc.x * v.x + fc.y * v.y + fc.z * v.z + fc.w * v.w;
            p += __shfl_xor(p, 1, 64);
            p += __shfl_xor(p, 2, 64);
            p += __shfl_xor(p, 4, 64);
            p += __shfl_xor(p, 8, 64);
            p = okc ? p : -INFINITY;            // group att (uniform in group)
            // cross-group max
            float tmx = fmaxf(p, __shfl_xor(p, 16, 64));
            float nm4 = fmaxf(tmx, __shfl_xor(tmx, 32, 64));
            float nm  = fmaxf(m, nm4);
            float scale = __expf(m - nm);       // m=-inf first iter -> 0
            float wg    = __expf(p - nm);       // 0 for invalid edges
            float sw = wg + __shfl_xor(wg, 16, 64);
            sw += __shfl_xor(sw, 32, 64);
            l = l * scale + sw;
            acc.x = acc.x * scale + wg * fc.x;
            acc.y = acc.y * scale + wg * fc.y;
            acc.z = acc.z * scale + wg * fc.z;
            acc.w = acc.w * scale + wg * fc.w;
            m = nm;
        }
        // combine the 4 group-accumulators (same dims, consistent scaling)
        acc.x += __shfl_xor(acc.x, 16, 64);
        acc.y += __shfl_xor(acc.y, 16, 64);
        acc.z += __shfl_xor(acc.z, 16, 64);
        acc.w += __shfl_xor(acc.w, 16, 64);
        acc.x += __shfl_xor(acc.x, 32, 64);
        acc.y += __shfl_xor(acc.y, 32, 64);
        acc.z += __shfl_xor(acc.z, 32, 64);
        acc.w += __shfl_xor(acc.w, 32, 64);
        float inv = 1.f / l;
        acc.x *= inv; acc.y *= inv; acc.z *= inv; acc.w *= inv;
    }
    if (lane < 16)
        *(float4*)&h_nb[(size_t)n * D + k * 4] = acc;
}

// ---------------- final: out = lrelu((f+h)@W1^T) + lrelu((f*h)@W2^T)
__global__ __launch_bounds__(256) void k_final(const float* __restrict__ feat,
                                               const float* __restrict__ h_nb,
                                               const float* __restrict__ W1,
                                               const float* __restrict__ W2,
                                               float* __restrict__ out, int N) {
    __shared__ float W1s[64][65];
    __shared__ float W2s[64][65];
    const int t = threadIdx.x;
    for (int idx = t; idx < 64 * 64; idx += 256) {
        int row = idx >> 6, col = idx & 63;
        W1s[row][col] = W1[idx];
        W2s[row][col] = W2[idx];
    }
    __syncthreads();
    const int lane = t & 63;
    const int wav  = t >> 6;
    for (int n = blockIdx.x * 4 + wav; n < N; n += gridDim.x * 4) {
        float f = feat[(size_t)n * D + lane];
        float h = h_nb[(size_t)n * D + lane];
        float xs = f + h;
        float xp = f * h;
        float a1 = 0.f, a2 = 0.f;
        #pragma unroll
        for (int d = 0; d < 64; ++d) {
            float s1 = __shfl(xs, d, 64);
            float s2 = __shfl(xp, d, 64);
            a1 += s1 * W1s[lane][d];
            a2 += s2 * W2s[lane][d];
        }
        float o1 = (a1 > 0.f) ? a1 : 0.01f * a1;
        float o2 = (a2 > 0.f) ? a2 : 0.01f * a2;
        out[(size_t)n * D + lane] = o1 + o2;
    }
}

extern "C" void kernel_launch(void* const* d_in, const int* in_sizes, int n_in,
                              void* d_out, int out_size, void* d_ws, size_t ws_size,
                              hipStream_t stream) {
    const float* feat  = (const float*)d_in[0];
    const float* relW  = (const float*)d_in[1];
    const float* relE  = (const float*)d_in[2];
    const float* W1    = (const float*)d_in[3];
    const float* W2    = (const float*)d_in[4];
    const int*   src   = (const int*)d_in[5];
    const int*   dst   = (const int*)d_in[6];
    const int*   etype = (const int*)d_in[7];
    float* out = (float*)d_out;

    const int N = in_sizes[0] / D;
    const int R = in_sizes[2] / D;
    const int E = in_sizes[5];

    char* w = (char*)d_ws;
    size_t off = 0;
    auto alloc = [&](size_t bytes) -> void* {
        void* p = w + off;
        off = (off + bytes + 255) & ~(size_t)255;
        return p;
    };
    unsigned short* varr = (unsigned short*)alloc((size_t)N * R * D * sizeof(unsigned short));
    float* h_nb   = (float*)alloc((size_t)N * D * sizeof(float));
    int* offsets  = (int*)alloc((size_t)(N + 1) * sizeof(int));
    int* tscan    = (int*)alloc((size_t)N * sizeof(int));
    int* cursor   = (int*)alloc((size_t)N * sizeof(int));
    int* deg      = (int*)alloc((size_t)N * sizeof(int));
    int* bsum     = (int*)alloc(2048 * sizeof(int));
    int* bofs     = (int*)alloc(2048 * sizeof(int));
    int* spack    = (int*)alloc((size_t)E * sizeof(int));
    size_t wfrag = (size_t)R * 4 * 2 * 64 * 8;
    unsigned short* B1h = (unsigned short*)alloc(wfrag * sizeof(unsigned short));
    unsigned short* B1l = (unsigned short*)alloc(wfrag * sizeof(unsigned short));
    unsigned short* B2h = (unsigned short*)alloc(wfrag * sizeof(unsigned short));
    unsigned short* B2l = (unsigned short*)alloc(wfrag * sizeof(unsigned short));
    (void)ws_size; (void)n_in; (void)out_size;

    const int NB = (N + 1023) / 1024;

    k_wsplit<<<(2 * R * 512 + 255) / 256, 256, 0, stream>>>(relW, B1h, B1l, B2h, B2l, R);
    hipMemsetAsync(deg, 0, (size_t)N * sizeof(int), stream);
    k_hist<<<(E + 255) / 256, 256, 0, stream>>>(dst, deg, E);
    k_scan1<<<NB, 1024, 0, stream>>>(deg, tscan, bsum, N);
    k_scan2<<<1, 1024, 0, stream>>>(bsum, bofs, NB);
    k_scan3<<<(N + 1 + 255) / 256, 256, 0, stream>>>(tscan, bofs, offsets, cursor, N);
    k_scatter<<<(E + 255) / 256, 256, 0, stream>>>(src, dst, etype, cursor, spack, E);
    k_projv<<<(N + 127) / 128, 256, 0, stream>>>(feat, B1h, B1l, B2h, B2l, relE, varr, N, R);
    k_fused2<<<(N + 3) / 4, 256, 0, stream>>>(varr, feat, offsets, spack, h_nb, N, R);
    k_final<<<1024, 256, 0, stream>>>(feat, h_nb, W1, W2, out, N);
}

// Round 7
// 594.236 us; speedup vs baseline: 1.5403x; 1.0426x over previous
//
#include <hip/hip_runtime.h>
#include <math.h>

#define D 64

typedef __attribute__((ext_vector_type(8))) short bf16x8;
typedef __attribute__((ext_vector_type(4))) float f32x4;

static __device__ __forceinline__ unsigned short f2bf(float f) {
    unsigned int u = __float_as_uint(f);
    unsigned int r = (u + 0x7FFFu + ((u >> 16) & 1u)) >> 16;  // RNE
    return (unsigned short)r;
}
static __device__ __forceinline__ float bf2f(unsigned short h) {
    return __uint_as_float(((unsigned int)h) << 16);
}

#if defined(__has_builtin)
#if __has_builtin(__builtin_amdgcn_cvt_pk_bf16_f32)
#define HAVE_PK_BF16 1
#endif
#endif

static __device__ __forceinline__ unsigned int pk2bf(float a, float b) {
#ifdef HAVE_PK_BF16
    auto v = __builtin_amdgcn_cvt_pk_bf16_f32(a, b);   // low=a, high=b
    return *(unsigned int*)&v;
#else
    return (unsigned int)f2bf(a) | ((unsigned int)f2bf(b) << 16);
#endif
}

// tanh(x) = 1 - 2/(e^{2x}+1); inf-safe at extremes (no clamp needed)
static __device__ __forceinline__ float fast_tanh(float x) {
    float e = __expf(2.f * x);
    float r = __builtin_amdgcn_rcpf(e + 1.f);
    return 1.f - 2.f * r;
}

typedef __attribute__((address_space(1))) const unsigned int as1_uint;
typedef __attribute__((address_space(3))) unsigned int as3_uint;
static __device__ __forceinline__ void dma16(const void* g, void* l) {
    // async global->LDS, 16B/lane; LDS dest = uniform base + lane*16
    __builtin_amdgcn_global_load_lds((as1_uint*)g, (as3_uint*)l, 16, 0, 0);
}

// ---------------- pre-split W into MFMA B-fragment-ordered hi/lo bf16 arrays.
// B1 (GEMM1, P=feat@W):   element W[r][d=kb*32+q*8+j][o=c*16+m]
// B2 (GEMM2, V=u@W^T):    element W[r][d=c*16+m][o=kb*32+q*8+j]
// layout: [r][c][kb][lane=q*16+m][j]  -> chunk (r, c*2+kb) = 64 lanes x 16B
__global__ __launch_bounds__(256) void k_wsplit(const float* __restrict__ W,
                                                unsigned short* __restrict__ B1h,
                                                unsigned short* __restrict__ B1l,
                                                unsigned short* __restrict__ B2h,
                                                unsigned short* __restrict__ B2l,
                                                int R) {
    int idx = blockIdx.x * 256 + threadIdx.x;
    int per_g = R * 512;
    if (idx >= 2 * per_g) return;
    int g = idx / per_g;
    int rest = idx % per_g;
    int r = rest >> 9;
    int rest2 = rest & 511;
    int c = rest2 >> 7;
    int kb = (rest2 >> 6) & 1;
    int lane = rest2 & 63;
    int m = lane & 15, q = lane >> 4;
    bf16x8 hv, lv;
    #pragma unroll
    for (int j = 0; j < 8; ++j) {
        float v;
        if (g == 0) v = W[(size_t)r * 4096 + (kb * 32 + q * 8 + j) * 64 + (c * 16 + m)];
        else        v = W[(size_t)r * 4096 + (c * 16 + m) * 64 + (kb * 32 + q * 8 + j)];
        unsigned short h = f2bf(v);
        hv[j] = (short)h;
        lv[j] = (short)f2bf(v - bf2f(h));
    }
    size_t off = ((((size_t)r * 4 + c) * 2 + kb) * 64 + lane) * 8;
    unsigned short* ph = (g == 0) ? B1h : B2h;
    unsigned short* pl = (g == 0) ? B1l : B2l;
    *(bf16x8*)&ph[off] = hv;
    *(bf16x8*)&pl[off] = lv;
}

// ---------------- fused proj+V: B-frags DMA'd cooperatively into double-buffered
// LDS (global_load_lds w=16), A-frags in registers, one barrier per r.
// V stored permuted: Vstore[n][r][m*4+c] = V_true[n][r][c*16+m].
__global__ __launch_bounds__(256, 2) void k_projv(const float* __restrict__ feat,
                                                  const unsigned short* __restrict__ B1h,
                                                  const unsigned short* __restrict__ B1l,
                                                  const unsigned short* __restrict__ B2h,
                                                  const unsigned short* __restrict__ B2l,
                                                  const float* __restrict__ emb,
                                                  unsigned short* __restrict__ V,
                                                  int N, int R) {
    const int n0 = blockIdx.x * 128;
    // chunk = arr*8 + c*2 + kb ; arr: 0=B1h 1=B1l 2=B2h 3=B2l
    __shared__ __align__(16) unsigned short Bbuf[2][32][512];
    __shared__ __align__(16) unsigned short Us[4][2048];
    const int t = threadIdx.x;
    const int lane = t & 63, w = t >> 6;
    const int m = lane & 15, q = lane >> 4;

    // ---- A-frags direct from global, split hi/lo in-register
    bf16x8 ah[2][2], al[2][2];
    #pragma unroll
    for (int s = 0; s < 2; ++s) {
        int n = n0 + w * 32 + s * 16 + m;
        const float* rowp = feat + (size_t)n * D;
        #pragma unroll
        for (int kb = 0; kb < 2; ++kb) {
            int d0 = kb * 32 + q * 8;
            float4 v0 = make_float4(0.f, 0.f, 0.f, 0.f), v1 = v0;
            if (n < N) { v0 = *(const float4*)(rowp + d0); v1 = *(const float4*)(rowp + d0 + 4); }
            float vals[8] = {v0.x, v0.y, v0.z, v0.w, v1.x, v1.y, v1.z, v1.w};
            bf16x8 hv, lv;
            #pragma unroll
            for (int j = 0; j < 8; ++j) {
                unsigned short h = f2bf(vals[j]);
                hv[j] = (short)h;
                lv[j] = (short)f2bf(vals[j] - bf2f(h));
            }
            ah[s][kb] = hv; al[s][kb] = lv;
        }
    }

    // wave w DMAs array w (8 chunks x 1KB) for relation r into Bbuf[buf]
    const unsigned short* warr = (w == 0) ? B1h : (w == 1) ? B1l : (w == 2) ? B2h : B2l;
    auto stage = [&](int r, int buf) {
        const unsigned short* gp = warr + (size_t)r * 4096 + lane * 8;
        #pragma unroll
        for (int i = 0; i < 8; ++i)
            dma16(gp + i * 512, &Bbuf[buf][w * 8 + i][0]);
    };

    stage(0, 0);
    __syncthreads();

    for (int r = 0; r < R; ++r) {
        const int cur = r & 1, nxt = cur ^ 1;
        if (r + 1 < R) stage(r + 1, nxt);   // async prefetch, drained by end barrier

        float em[4];
        #pragma unroll
        for (int c = 0; c < 4; ++c) em[c] = emb[r * 64 + c * 16 + m];

        // ---------- GEMM1: P = feat @ W_r (3-term split), B-frags from LDS
        f32x4 acc[4][2];
        #pragma unroll
        for (int c = 0; c < 4; ++c)
            #pragma unroll
            for (int s = 0; s < 2; ++s) acc[c][s] = (f32x4){0.f, 0.f, 0.f, 0.f};
        #pragma unroll
        for (int c = 0; c < 4; ++c) {
            bf16x8 bh[2], bl[2];
            #pragma unroll
            for (int kb = 0; kb < 2; ++kb) {
                bh[kb] = *(const bf16x8*)&Bbuf[cur][c * 2 + kb][lane * 8];
                bl[kb] = *(const bf16x8*)&Bbuf[cur][8 + c * 2 + kb][lane * 8];
            }
            #pragma unroll
            for (int kb = 0; kb < 2; ++kb)
                #pragma unroll
                for (int s = 0; s < 2; ++s) {
                    acc[c][s] = __builtin_amdgcn_mfma_f32_16x16x32_bf16(ah[s][kb], bh[kb], acc[c][s], 0, 0, 0);
                    acc[c][s] = __builtin_amdgcn_mfma_f32_16x16x32_bf16(al[s][kb], bh[kb], acc[c][s], 0, 0, 0);
                    acc[c][s] = __builtin_amdgcn_mfma_f32_16x16x32_bf16(ah[s][kb], bl[kb], acc[c][s], 0, 0, 0);
                }
        }

        // ---------- epilogue 1: u = tanh(P+emb) -> swizzled wave-private Us
        #pragma unroll
        for (int s = 0; s < 2; ++s)
            #pragma unroll
            for (int c = 0; c < 4; ++c) {
                int o = c * 16 + m;
                int kb2 = o >> 5;
                int q2 = (o >> 3) & 3;
                int j = o & 7;
                int Fb = (s * 2 + kb2) * 64 + q2 * 16 + q * 4;
                #pragma unroll
                for (int i = 0; i < 4; i += 2) {
                    float t0 = fast_tanh(acc[c][s][i] + em[c]);
                    float t1 = fast_tanh(acc[c][s][i + 1] + em[c]);
                    unsigned int pk = pk2bf(t0, t1);
                    Us[w][((Fb + i) ^ q2) * 8 + j]     = (unsigned short)(pk & 0xFFFF);
                    Us[w][((Fb + i + 1) ^ q2) * 8 + j] = (unsigned short)(pk >> 16);
                }
            }

        // ---------- GEMM2: V = u @ W_r^T (2-term split)
        bf16x8 ua[2][2];
        #pragma unroll
        for (int s = 0; s < 2; ++s)
            #pragma unroll
            for (int kb = 0; kb < 2; ++kb) {
                int F = (s * 2 + kb) * 64 + lane;
                ua[s][kb] = *(const bf16x8*)&Us[w][(F ^ (lane >> 4)) * 8];
            }
        f32x4 acc2[4][2];
        #pragma unroll
        for (int c = 0; c < 4; ++c)
            #pragma unroll
            for (int s = 0; s < 2; ++s) acc2[c][s] = (f32x4){0.f, 0.f, 0.f, 0.f};
        #pragma unroll
        for (int c = 0; c < 4; ++c) {
            bf16x8 bh[2], bl[2];
            #pragma unroll
            for (int kb = 0; kb < 2; ++kb) {
                bh[kb] = *(const bf16x8*)&Bbuf[cur][16 + c * 2 + kb][lane * 8];
                bl[kb] = *(const bf16x8*)&Bbuf[cur][24 + c * 2 + kb][lane * 8];
            }
            #pragma unroll
            for (int kb = 0; kb < 2; ++kb)
                #pragma unroll
                for (int s = 0; s < 2; ++s) {
                    acc2[c][s] = __builtin_amdgcn_mfma_f32_16x16x32_bf16(ua[s][kb], bh[kb], acc2[c][s], 0, 0, 0);
                    acc2[c][s] = __builtin_amdgcn_mfma_f32_16x16x32_bf16(ua[s][kb], bl[kb], acc2[c][s], 0, 0, 0);
                }
        }

        // ---------- store V permuted (8B vector per lane)
        #pragma unroll
        for (int s = 0; s < 2; ++s)
            #pragma unroll
            for (int i = 0; i < 4; ++i) {
                int n = n0 + w * 32 + s * 16 + q * 4 + i;
                if (n < N) {
                    uint2 pv;
                    pv.x = pk2bf(acc2[0][s][i], acc2[1][s][i]);
                    pv.y = pk2bf(acc2[2][s][i], acc2[3][s][i]);
                    *(uint2*)&V[((size_t)n * R + r) * 64 + m * 4] = pv;
                }
            }

        // drains the nxt DMA (vmcnt) and fences all reads of cur
        __syncthreads();
    }
}

// ---------------- histogram of dst
__global__ __launch_bounds__(256) void k_hist(const int* __restrict__ dst, int* __restrict__ deg, int E) {
    int e = blockIdx.x * 256 + threadIdx.x;
    if (e < E) atomicAdd(&deg[dst[e]], 1);
}

// ---------------- scan step 1
__global__ __launch_bounds__(1024) void k_scan1(const int* __restrict__ deg, int* __restrict__ tscan,
                                                int* __restrict__ bsum, int N) {
    __shared__ int s[1024];
    const int t = threadIdx.x;
    const int i = blockIdx.x * 1024 + t;
    int v = (i < N) ? deg[i] : 0;
    s[t] = v;
    __syncthreads();
    for (int off = 1; off < 1024; off <<= 1) {
        int tmp = (t >= off) ? s[t - off] : 0;
        __syncthreads();
        s[t] += tmp;
        __syncthreads();
    }
    if (i < N) tscan[i] = s[t];
    if (t == 1023) bsum[blockIdx.x] = s[1023];
}

// ---------------- scan step 2
__global__ __launch_bounds__(1024) void k_scan2(const int* __restrict__ bsum, int* __restrict__ bofs, int NB) {
    __shared__ int s[1024];
    const int t = threadIdx.x;
    int carry = 0;
    for (int b0 = 0; b0 < NB; b0 += 1024) {
        int i = b0 + t;
        int v = (i < NB) ? bsum[i] : 0;
        s[t] = v;
        __syncthreads();
        for (int off = 1; off < 1024; off <<= 1) {
            int tmp = (t >= off) ? s[t - off] : 0;
            __syncthreads();
            s[t] += tmp;
            __syncthreads();
        }
        if (i < NB) bofs[i] = carry + s[t] - v;
        int tot = s[1023];
        __syncthreads();
        carry += tot;
    }
}

// ---------------- scan step 3
__global__ __launch_bounds__(256) void k_scan3(const int* __restrict__ tscan, const int* __restrict__ bofs,
                                               int* __restrict__ offsets, int* __restrict__ cursor, int N) {
    int i = blockIdx.x * 256 + threadIdx.x;
    if (i <= N) {
        int v = (i == 0) ? 0 : (tscan[i - 1] + bofs[(i - 1) >> 10]);
        offsets[i] = v;
        if (i < N) cursor[i] = v;
    }
}

// ---------------- scatter edges into dst-sorted order
__global__ __launch_bounds__(256) void k_scatter(const int* __restrict__ src, const int* __restrict__ dst,
                                                 const int* __restrict__ etype, int* __restrict__ cursor,
                                                 int* __restrict__ spack, int E) {
    int e = blockIdx.x * 256 + threadIdx.x;
    if (e < E) {
        int d = dst[e];
        int p = atomicAdd(&cursor[d], 1);
        spack[p] = src[e] | (etype[e] << 20);
    }
}

// ---------------- fused att + softmax + aggregation: 4 edges per wave-iteration.
__global__ __launch_bounds__(256) void k_fused2(const unsigned short* __restrict__ V,
                                                const float* __restrict__ feat,
                                                const int* __restrict__ offsets,
                                                const int* __restrict__ spack,
                                                float* __restrict__ h_nb,
                                                int N, int R) {
    const int lane = threadIdx.x & 63;
    const int wav  = threadIdx.x >> 6;
    const int g    = lane >> 4;     // edge-group 0..3
    const int k    = lane & 15;     // lane-in-group (dims 4k..4k+3)
    const int n = blockIdx.x * 4 + wav;
    __shared__ float vlds[4][1024];   // [wave][r*64 + dim], natural order, fp32
    if (n >= N) return;

    const unsigned int* v32 = (const unsigned int*)(V + (size_t)n * R * D);
    #pragma unroll
    for (int j = 0; j < 8; ++j) {
        int uidx = j * 64 + lane;
        unsigned int u = v32[uidx];
        int r  = uidx >> 5;
        int k2 = uidx & 31;
        int mm = k2 >> 1;
        int cc = (k2 & 1) * 2;
        int o  = cc * 16 + mm;
        vlds[wav][r * 64 + o]      = bf2f((unsigned short)(u & 0xFFFF));
        vlds[wav][r * 64 + o + 16] = bf2f((unsigned short)(u >> 16));
    }

    const int beg = offsets[n], end = offsets[n + 1];
    float m = -INFINITY, l = 0.f;
    float4 acc = make_float4(0.f, 0.f, 0.f, 0.f);

    if (beg < end) {
        int e = beg + g;
        bool ok = e < end;
        int pk = spack[ok ? e : (end - 1)];
        float4 f = *(const float4*)&feat[(size_t)(pk & 0xFFFFF) * D + k * 4];

        for (int i = beg; i < end; i += 4) {
            const int   et  = pk >> 20;
            const float4 fc = f;
            const bool  okc = ok;
            int e2 = i + 4 + g;
            ok = e2 < end;
            pk = spack[ok ? e2 : (end - 1)];
            f = *(const float4*)&feat[(size_t)(pk & 0xFFFFF) * D + k * 4];

            float4 v = *(const float4*)&vlds[wav][et * 64 + k * 4];
            float p = fc.x * v.x + fc.y * v.y + fc.z * v.z + fc.w * v.w;
            p += __shfl_xor(p, 1, 64);
            p += __shfl_xor(p, 2, 64);
            p += __shfl_xor(p, 4, 64);
            p += __shfl_xor(p, 8, 64);
            p = okc ? p : -INFINITY;
            float tmx = fmaxf(p, __shfl_xor(p, 16, 64));
            float nm4 = fmaxf(tmx, __shfl_xor(tmx, 32, 64));
            float nm  = fmaxf(m, nm4);
            float scale = __expf(m - nm);
            float wg    = __expf(p - nm);
            float sw = wg + __shfl_xor(wg, 16, 64);
            sw += __shfl_xor(sw, 32, 64);
            l = l * scale + sw;
            acc.x = acc.x * scale + wg * fc.x;
            acc.y = acc.y * scale + wg * fc.y;
            acc.z = acc.z * scale + wg * fc.z;
            acc.w = acc.w * scale + wg * fc.w;
            m = nm;
        }
        acc.x += __shfl_xor(acc.x, 16, 64);
        acc.y += __shfl_xor(acc.y, 16, 64);
        acc.z += __shfl_xor(acc.z, 16, 64);
        acc.w += __shfl_xor(acc.w, 16, 64);
        acc.x += __shfl_xor(acc.x, 32, 64);
        acc.y += __shfl_xor(acc.y, 32, 64);
        acc.z += __shfl_xor(acc.z, 32, 64);
        acc.w += __shfl_xor(acc.w, 32, 64);
        float inv = 1.f / l;
        acc.x *= inv; acc.y *= inv; acc.z *= inv; acc.w *= inv;
    }
    if (lane < 16)
        *(float4*)&h_nb[(size_t)n * D + k * 4] = acc;
}

// ---------------- final: out = lrelu((f+h)@W1^T) + lrelu((f*h)@W2^T)
__global__ __launch_bounds__(256) void k_final(const float* __restrict__ feat,
                                               const float* __restrict__ h_nb,
                                               const float* __restrict__ W1,
                                               const float* __restrict__ W2,
                                               float* __restrict__ out, int N) {
    __shared__ float W1s[64][65];
    __shared__ float W2s[64][65];
    const int t = threadIdx.x;
    for (int idx = t; idx < 64 * 64; idx += 256) {
        int row = idx >> 6, col = idx & 63;
        W1s[row][col] = W1[idx];
        W2s[row][col] = W2[idx];
    }
    __syncthreads();
    const int lane = t & 63;
    const int wav  = t >> 6;
    for (int n = blockIdx.x * 4 + wav; n < N; n += gridDim.x * 4) {
        float f = feat[(size_t)n * D + lane];
        float h = h_nb[(size_t)n * D + lane];
        float xs = f + h;
        float xp = f * h;
        float a1 = 0.f, a2 = 0.f;
        #pragma unroll
        for (int d = 0; d < 64; ++d) {
            float s1 = __shfl(xs, d, 64);
            float s2 = __shfl(xp, d, 64);
            a1 += s1 * W1s[lane][d];
            a2 += s2 * W2s[lane][d];
        }
        float o1 = (a1 > 0.f) ? a1 : 0.01f * a1;
        float o2 = (a2 > 0.f) ? a2 : 0.01f * a2;
        out[(size_t)n * D + lane] = o1 + o2;
    }
}

extern "C" void kernel_launch(void* const* d_in, const int* in_sizes, int n_in,
                              void* d_out, int out_size, void* d_ws, size_t ws_size,
                              hipStream_t stream) {
    const float* feat  = (const float*)d_in[0];
    const float* relW  = (const float*)d_in[1];
    const float* relE  = (const float*)d_in[2];
    const float* W1    = (const float*)d_in[3];
    const float* W2    = (const float*)d_in[4];
    const int*   src   = (const int*)d_in[5];
    const int*   dst   = (const int*)d_in[6];
    const int*   etype = (const int*)d_in[7];
    float* out = (float*)d_out;

    const int N = in_sizes[0] / D;
    const int R = in_sizes[2] / D;
    const int E = in_sizes[5];

    char* w = (char*)d_ws;
    size_t off = 0;
    auto alloc = [&](size_t bytes) -> void* {
        void* p = w + off;
        off = (off + bytes + 255) & ~(size_t)255;
        return p;
    };
    unsigned short* varr = (unsigned short*)alloc((size_t)N * R * D * sizeof(unsigned short));
    float* h_nb   = (float*)alloc((size_t)N * D * sizeof(float));
    int* offsets  = (int*)alloc((size_t)(N + 1) * sizeof(int));
    int* tscan    = (int*)alloc((size_t)N * sizeof(int));
    int* cursor   = (int*)alloc((size_t)N * sizeof(int));
    int* deg      = (int*)alloc((size_t)N * sizeof(int));
    int* bsum     = (int*)alloc(2048 * sizeof(int));
    int* bofs     = (int*)alloc(2048 * sizeof(int));
    int* spack    = (int*)alloc((size_t)E * sizeof(int));
    size_t wfrag = (size_t)R * 4 * 2 * 64 * 8;
    unsigned short* B1h = (unsigned short*)alloc(wfrag * sizeof(unsigned short));
    unsigned short* B1l = (unsigned short*)alloc(wfrag * sizeof(unsigned short));
    unsigned short* B2h = (unsigned short*)alloc(wfrag * sizeof(unsigned short));
    unsigned short* B2l = (unsigned short*)alloc(wfrag * sizeof(unsigned short));
    (void)ws_size; (void)n_in; (void)out_size;

    const int NB = (N + 1023) / 1024;

    k_wsplit<<<(2 * R * 512 + 255) / 256, 256, 0, stream>>>(relW, B1h, B1l, B2h, B2l, R);
    hipMemsetAsync(deg, 0, (size_t)N * sizeof(int), stream);
    k_hist<<<(E + 255) / 256, 256, 0, stream>>>(dst, deg, E);
    k_scan1<<<NB, 1024, 0, stream>>>(deg, tscan, bsum, N);
    k_scan2<<<1, 1024, 0, stream>>>(bsum, bofs, NB);
    k_scan3<<<(N + 1 + 255) / 256, 256, 0, stream>>>(tscan, bofs, offsets, cursor, N);
    k_scatter<<<(E + 255) / 256, 256, 0, stream>>>(src, dst, etype, cursor, spack, E);
    k_projv<<<(N + 127) / 128, 256, 0, stream>>>(feat, B1h, B1l, B2h, B2l, relE, varr, N, R);
    k_fused2<<<(N + 3) / 4, 256, 0, stream>>>(varr, feat, offsets, spack, h_nb, N, R);
    k_final<<<1024, 256, 0, stream>>>(feat, h_nb, W1, W2, out, N);
}

// Round 8
// 468.609 us; speedup vs baseline: 1.9532x; 1.2681x over previous
//
#include <hip/hip_runtime.h>
#include <math.h>

#define D 64

typedef __attribute__((ext_vector_type(8))) short bf16x8;
typedef __attribute__((ext_vector_type(4))) float f32x4;

static __device__ __forceinline__ unsigned short f2bf(float f) {
    unsigned int u = __float_as_uint(f);
    unsigned int r = (u + 0x7FFFu + ((u >> 16) & 1u)) >> 16;  // RNE
    return (unsigned short)r;
}
static __device__ __forceinline__ float bf2f(unsigned short h) {
    return __uint_as_float(((unsigned int)h) << 16);
}

#if defined(__has_builtin)
#if __has_builtin(__builtin_amdgcn_cvt_pk_bf16_f32)
#define HAVE_PK_BF16 1
#endif
#endif

static __device__ __forceinline__ unsigned int pk2bf(float a, float b) {
#ifdef HAVE_PK_BF16
    auto v = __builtin_amdgcn_cvt_pk_bf16_f32(a, b);   // low=a, high=b
    return *(unsigned int*)&v;
#else
    return (unsigned int)f2bf(a) | ((unsigned int)f2bf(b) << 16);
#endif
}

// tanh(x) = 1 - 2/(e^{2x}+1); inf-safe at extremes (no clamp needed)
static __device__ __forceinline__ float fast_tanh(float x) {
    float e = __expf(2.f * x);
    float r = __builtin_amdgcn_rcpf(e + 1.f);
    return 1.f - 2.f * r;
}

typedef __attribute__((address_space(1))) const unsigned int as1_uint;
typedef __attribute__((address_space(3))) unsigned int as3_uint;
static __device__ __forceinline__ void dma16(const void* g, void* l) {
    // async global->LDS, 16B/lane; LDS dest = uniform base + lane*16
    __builtin_amdgcn_global_load_lds((as1_uint*)g, (as3_uint*)l, 16, 0, 0);
}

// ---------------- pre-split W into MFMA B-fragment-ordered hi/lo bf16 arrays.
// B1 (GEMM1, P=feat@W):   element W[r][d=kb*32+q*8+j][o=c*16+m]
// B2 (GEMM2, V=u@W^T):    element W[r][d=c*16+m][o=kb*32+q*8+j]
// layout: [r][c][kb][lane=q*16+m][j]  -> chunk (r, c*2+kb) = 64 lanes x 16B
__global__ __launch_bounds__(256) void k_wsplit(const float* __restrict__ W,
                                                unsigned short* __restrict__ B1h,
                                                unsigned short* __restrict__ B1l,
                                                unsigned short* __restrict__ B2h,
                                                unsigned short* __restrict__ B2l,
                                                int R) {
    int idx = blockIdx.x * 256 + threadIdx.x;
    int per_g = R * 512;
    if (idx >= 2 * per_g) return;
    int g = idx / per_g;
    int rest = idx % per_g;
    int r = rest >> 9;
    int rest2 = rest & 511;
    int c = rest2 >> 7;
    int kb = (rest2 >> 6) & 1;
    int lane = rest2 & 63;
    int m = lane & 15, q = lane >> 4;
    bf16x8 hv, lv;
    #pragma unroll
    for (int j = 0; j < 8; ++j) {
        float v;
        if (g == 0) v = W[(size_t)r * 4096 + (kb * 32 + q * 8 + j) * 64 + (c * 16 + m)];
        else        v = W[(size_t)r * 4096 + (c * 16 + m) * 64 + (kb * 32 + q * 8 + j)];
        unsigned short h = f2bf(v);
        hv[j] = (short)h;
        lv[j] = (short)f2bf(v - bf2f(h));
    }
    size_t off = ((((size_t)r * 4 + c) * 2 + kb) * 64 + lane) * 8;
    unsigned short* ph = (g == 0) ? B1h : B2h;
    unsigned short* pl = (g == 0) ? B1l : B2l;
    *(bf16x8*)&ph[off] = hv;
    *(bf16x8*)&pl[off] = lv;
}

// ---------------- pre-split W1/W2 (for k_final): out = x @ Wk^T.
// B-frag element [d=kb*32+q*8+j][o=c*16+m] = Wk[(c*16+m)*64 + kb*32+q*8+j]
__global__ __launch_bounds__(256) void k_wsplit2(const float* __restrict__ W1,
                                                 const float* __restrict__ W2,
                                                 unsigned short* __restrict__ F1h,
                                                 unsigned short* __restrict__ F1l,
                                                 unsigned short* __restrict__ F2h,
                                                 unsigned short* __restrict__ F2l) {
    int idx = blockIdx.x * 256 + threadIdx.x;
    if (idx >= 1024) return;
    int g = idx >> 9;
    int rest2 = idx & 511;
    int c = rest2 >> 7;
    int kb = (rest2 >> 6) & 1;
    int lane = rest2 & 63;
    int m = lane & 15, q = lane >> 4;
    const float* W = g ? W2 : W1;
    bf16x8 hv, lv;
    #pragma unroll
    for (int j = 0; j < 8; ++j) {
        float v = W[(c * 16 + m) * 64 + kb * 32 + q * 8 + j];
        unsigned short h = f2bf(v);
        hv[j] = (short)h;
        lv[j] = (short)f2bf(v - bf2f(h));
    }
    size_t off = (((size_t)c * 2 + kb) * 64 + lane) * 8;
    unsigned short* ph = g ? F2h : F1h;
    unsigned short* pl = g ? F2l : F1l;
    *(bf16x8*)&ph[off] = hv;
    *(bf16x8*)&pl[off] = lv;
}

// ---------------- fused proj+V: B-frags DMA'd cooperatively into double-buffered
// LDS, A-frags in registers, one barrier per r. (unchanged from R7)
__global__ __launch_bounds__(256, 2) void k_projv(const float* __restrict__ feat,
                                                  const unsigned short* __restrict__ B1h,
                                                  const unsigned short* __restrict__ B1l,
                                                  const unsigned short* __restrict__ B2h,
                                                  const unsigned short* __restrict__ B2l,
                                                  const float* __restrict__ emb,
                                                  unsigned short* __restrict__ V,
                                                  int N, int R) {
    const int n0 = blockIdx.x * 128;
    __shared__ __align__(16) unsigned short Bbuf[2][32][512];
    __shared__ __align__(16) unsigned short Us[4][2048];
    const int t = threadIdx.x;
    const int lane = t & 63, w = t >> 6;
    const int m = lane & 15, q = lane >> 4;

    bf16x8 ah[2][2], al[2][2];
    #pragma unroll
    for (int s = 0; s < 2; ++s) {
        int n = n0 + w * 32 + s * 16 + m;
        const float* rowp = feat + (size_t)n * D;
        #pragma unroll
        for (int kb = 0; kb < 2; ++kb) {
            int d0 = kb * 32 + q * 8;
            float4 v0 = make_float4(0.f, 0.f, 0.f, 0.f), v1 = v0;
            if (n < N) { v0 = *(const float4*)(rowp + d0); v1 = *(const float4*)(rowp + d0 + 4); }
            float vals[8] = {v0.x, v0.y, v0.z, v0.w, v1.x, v1.y, v1.z, v1.w};
            bf16x8 hv, lv;
            #pragma unroll
            for (int j = 0; j < 8; ++j) {
                unsigned short h = f2bf(vals[j]);
                hv[j] = (short)h;
                lv[j] = (short)f2bf(vals[j] - bf2f(h));
            }
            ah[s][kb] = hv; al[s][kb] = lv;
        }
    }

    const unsigned short* warr = (w == 0) ? B1h : (w == 1) ? B1l : (w == 2) ? B2h : B2l;
    auto stage = [&](int r, int buf) {
        const unsigned short* gp = warr + (size_t)r * 4096 + lane * 8;
        #pragma unroll
        for (int i = 0; i < 8; ++i)
            dma16(gp + i * 512, &Bbuf[buf][w * 8 + i][0]);
    };

    stage(0, 0);
    __syncthreads();

    for (int r = 0; r < R; ++r) {
        const int cur = r & 1, nxt = cur ^ 1;
        if (r + 1 < R) stage(r + 1, nxt);

        float em[4];
        #pragma unroll
        for (int c = 0; c < 4; ++c) em[c] = emb[r * 64 + c * 16 + m];

        f32x4 acc[4][2];
        #pragma unroll
        for (int c = 0; c < 4; ++c)
            #pragma unroll
            for (int s = 0; s < 2; ++s) acc[c][s] = (f32x4){0.f, 0.f, 0.f, 0.f};
        #pragma unroll
        for (int c = 0; c < 4; ++c) {
            bf16x8 bh[2], bl[2];
            #pragma unroll
            for (int kb = 0; kb < 2; ++kb) {
                bh[kb] = *(const bf16x8*)&Bbuf[cur][c * 2 + kb][lane * 8];
                bl[kb] = *(const bf16x8*)&Bbuf[cur][8 + c * 2 + kb][lane * 8];
            }
            #pragma unroll
            for (int kb = 0; kb < 2; ++kb)
                #pragma unroll
                for (int s = 0; s < 2; ++s) {
                    acc[c][s] = __builtin_amdgcn_mfma_f32_16x16x32_bf16(ah[s][kb], bh[kb], acc[c][s], 0, 0, 0);
                    acc[c][s] = __builtin_amdgcn_mfma_f32_16x16x32_bf16(al[s][kb], bh[kb], acc[c][s], 0, 0, 0);
                    acc[c][s] = __builtin_amdgcn_mfma_f32_16x16x32_bf16(ah[s][kb], bl[kb], acc[c][s], 0, 0, 0);
                }
        }

        #pragma unroll
        for (int s = 0; s < 2; ++s)
            #pragma unroll
            for (int c = 0; c < 4; ++c) {
                int o = c * 16 + m;
                int kb2 = o >> 5;
                int q2 = (o >> 3) & 3;
                int j = o & 7;
                int Fb = (s * 2 + kb2) * 64 + q2 * 16 + q * 4;
                #pragma unroll
                for (int i = 0; i < 4; i += 2) {
                    float t0 = fast_tanh(acc[c][s][i] + em[c]);
                    float t1 = fast_tanh(acc[c][s][i + 1] + em[c]);
                    unsigned int pk = pk2bf(t0, t1);
                    Us[w][((Fb + i) ^ q2) * 8 + j]     = (unsigned short)(pk & 0xFFFF);
                    Us[w][((Fb + i + 1) ^ q2) * 8 + j] = (unsigned short)(pk >> 16);
                }
            }

        bf16x8 ua[2][2];
        #pragma unroll
        for (int s = 0; s < 2; ++s)
            #pragma unroll
            for (int kb = 0; kb < 2; ++kb) {
                int F = (s * 2 + kb) * 64 + lane;
                ua[s][kb] = *(const bf16x8*)&Us[w][(F ^ (lane >> 4)) * 8];
            }
        f32x4 acc2[4][2];
        #pragma unroll
        for (int c = 0; c < 4; ++c)
            #pragma unroll
            for (int s = 0; s < 2; ++s) acc2[c][s] = (f32x4){0.f, 0.f, 0.f, 0.f};
        #pragma unroll
        for (int c = 0; c < 4; ++c) {
            bf16x8 bh[2], bl[2];
            #pragma unroll
            for (int kb = 0; kb < 2; ++kb) {
                bh[kb] = *(const bf16x8*)&Bbuf[cur][16 + c * 2 + kb][lane * 8];
                bl[kb] = *(const bf16x8*)&Bbuf[cur][24 + c * 2 + kb][lane * 8];
            }
            #pragma unroll
            for (int kb = 0; kb < 2; ++kb)
                #pragma unroll
                for (int s = 0; s < 2; ++s) {
                    acc2[c][s] = __builtin_amdgcn_mfma_f32_16x16x32_bf16(ua[s][kb], bh[kb], acc2[c][s], 0, 0, 0);
                    acc2[c][s] = __builtin_amdgcn_mfma_f32_16x16x32_bf16(ua[s][kb], bl[kb], acc2[c][s], 0, 0, 0);
                }
        }

        #pragma unroll
        for (int s = 0; s < 2; ++s)
            #pragma unroll
            for (int i = 0; i < 4; ++i) {
                int n = n0 + w * 32 + s * 16 + q * 4 + i;
                if (n < N) {
                    uint2 pv;
                    pv.x = pk2bf(acc2[0][s][i], acc2[1][s][i]);
                    pv.y = pk2bf(acc2[2][s][i], acc2[3][s][i]);
                    *(uint2*)&V[((size_t)n * R + r) * 64 + m * 4] = pv;
                }
            }

        __syncthreads();
    }
}

// ---------------- histogram of dst
__global__ __launch_bounds__(256) void k_hist(const int* __restrict__ dst, int* __restrict__ deg, int E) {
    int e = blockIdx.x * 256 + threadIdx.x;
    if (e < E) atomicAdd(&deg[dst[e]], 1);
}

// ---------------- scan step 1
__global__ __launch_bounds__(1024) void k_scan1(const int* __restrict__ deg, int* __restrict__ tscan,
                                                int* __restrict__ bsum, int N) {
    __shared__ int s[1024];
    const int t = threadIdx.x;
    const int i = blockIdx.x * 1024 + t;
    int v = (i < N) ? deg[i] : 0;
    s[t] = v;
    __syncthreads();
    for (int off = 1; off < 1024; off <<= 1) {
        int tmp = (t >= off) ? s[t - off] : 0;
        __syncthreads();
        s[t] += tmp;
        __syncthreads();
    }
    if (i < N) tscan[i] = s[t];
    if (t == 1023) bsum[blockIdx.x] = s[1023];
}

// ---------------- scan step 2
__global__ __launch_bounds__(1024) void k_scan2(const int* __restrict__ bsum, int* __restrict__ bofs, int NB) {
    __shared__ int s[1024];
    const int t = threadIdx.x;
    int carry = 0;
    for (int b0 = 0; b0 < NB; b0 += 1024) {
        int i = b0 + t;
        int v = (i < NB) ? bsum[i] : 0;
        s[t] = v;
        __syncthreads();
        for (int off = 1; off < 1024; off <<= 1) {
            int tmp = (t >= off) ? s[t - off] : 0;
            __syncthreads();
            s[t] += tmp;
            __syncthreads();
        }
        if (i < NB) bofs[i] = carry + s[t] - v;
        int tot = s[1023];
        __syncthreads();
        carry += tot;
    }
}

// ---------------- scan step 3
__global__ __launch_bounds__(256) void k_scan3(const int* __restrict__ tscan, const int* __restrict__ bofs,
                                               int* __restrict__ offsets, int* __restrict__ cursor, int N) {
    int i = blockIdx.x * 256 + threadIdx.x;
    if (i <= N) {
        int v = (i == 0) ? 0 : (tscan[i - 1] + bofs[(i - 1) >> 10]);
        offsets[i] = v;
        if (i < N) cursor[i] = v;
    }
}

// ---------------- scatter edges into dst-sorted order
__global__ __launch_bounds__(256) void k_scatter(const int* __restrict__ src, const int* __restrict__ dst,
                                                 const int* __restrict__ etype, int* __restrict__ cursor,
                                                 int* __restrict__ spack, int E) {
    int e = blockIdx.x * 256 + threadIdx.x;
    if (e < E) {
        int d = dst[e];
        int p = atomicAdd(&cursor[d], 1);
        spack[p] = src[e] | (etype[e] << 20);
    }
}

// ---------------- fused att + softmax + aggregation: 4 edges per wave-iteration.
__global__ __launch_bounds__(256) void k_fused2(const unsigned short* __restrict__ V,
                                                const float* __restrict__ feat,
                                                const int* __restrict__ offsets,
                                                const int* __restrict__ spack,
                                                float* __restrict__ h_nb,
                                                int N, int R) {
    const int lane = threadIdx.x & 63;
    const int wav  = threadIdx.x >> 6;
    const int g    = lane >> 4;
    const int k    = lane & 15;
    const int n = blockIdx.x * 4 + wav;
    __shared__ float vlds[4][1024];
    if (n >= N) return;

    const unsigned int* v32 = (const unsigned int*)(V + (size_t)n * R * D);
    #pragma unroll
    for (int j = 0; j < 8; ++j) {
        int uidx = j * 64 + lane;
        unsigned int u = v32[uidx];
        int r  = uidx >> 5;
        int k2 = uidx & 31;
        int mm = k2 >> 1;
        int cc = (k2 & 1) * 2;
        int o  = cc * 16 + mm;
        vlds[wav][r * 64 + o]      = bf2f((unsigned short)(u & 0xFFFF));
        vlds[wav][r * 64 + o + 16] = bf2f((unsigned short)(u >> 16));
    }

    const int beg = offsets[n], end = offsets[n + 1];
    float m = -INFINITY, l = 0.f;
    float4 acc = make_float4(0.f, 0.f, 0.f, 0.f);

    if (beg < end) {
        int e = beg + g;
        bool ok = e < end;
        int pk = spack[ok ? e : (end - 1)];
        float4 f = *(const float4*)&feat[(size_t)(pk & 0xFFFFF) * D + k * 4];

        for (int i = beg; i < end; i += 4) {
            const int   et  = pk >> 20;
            const float4 fc = f;
            const bool  okc = ok;
            int e2 = i + 4 + g;
            ok = e2 < end;
            pk = spack[ok ? e2 : (end - 1)];
            f = *(const float4*)&feat[(size_t)(pk & 0xFFFFF) * D + k * 4];

            float4 v = *(const float4*)&vlds[wav][et * 64 + k * 4];
            float p = fc.x * v.x + fc.y * v.y + fc.z * v.z + fc.w * v.w;
            p += __shfl_xor(p, 1, 64);
            p += __shfl_xor(p, 2, 64);
            p += __shfl_xor(p, 4, 64);
            p += __shfl_xor(p, 8, 64);
            p = okc ? p : -INFINITY;
            float tmx = fmaxf(p, __shfl_xor(p, 16, 64));
            float nm4 = fmaxf(tmx, __shfl_xor(tmx, 32, 64));
            float nm  = fmaxf(m, nm4);
            float scale = __expf(m - nm);
            float wg    = __expf(p - nm);
            float sw = wg + __shfl_xor(wg, 16, 64);
            sw += __shfl_xor(sw, 32, 64);
            l = l * scale + sw;
            acc.x = acc.x * scale + wg * fc.x;
            acc.y = acc.y * scale + wg * fc.y;
            acc.z = acc.z * scale + wg * fc.z;
            acc.w = acc.w * scale + wg * fc.w;
            m = nm;
        }
        acc.x += __shfl_xor(acc.x, 16, 64);
        acc.y += __shfl_xor(acc.y, 16, 64);
        acc.z += __shfl_xor(acc.z, 16, 64);
        acc.w += __shfl_xor(acc.w, 16, 64);
        acc.x += __shfl_xor(acc.x, 32, 64);
        acc.y += __shfl_xor(acc.y, 32, 64);
        acc.z += __shfl_xor(acc.z, 32, 64);
        acc.w += __shfl_xor(acc.w, 32, 64);
        float inv = 1.f / l;
        acc.x *= inv; acc.y *= inv; acc.z *= inv; acc.w *= inv;
    }
    if (lane < 16)
        *(float4*)&h_nb[(size_t)n * D + k * 4] = acc;
}

// ---------------- final via MFMA: out = lrelu((f+h)@W1^T) + lrelu((f*h)@W2^T)
// 128 nodes/block; W1/W2 frags DMA'd to LDS once; xs/xp split-bf16 A-frags.
__global__ __launch_bounds__(256, 2) void k_final(const float* __restrict__ feat,
                                                  const float* __restrict__ h_nb,
                                                  const unsigned short* __restrict__ F1h,
                                                  const unsigned short* __restrict__ F1l,
                                                  const unsigned short* __restrict__ F2h,
                                                  const unsigned short* __restrict__ F2l,
                                                  float* __restrict__ out, int N) {
    const int n0 = blockIdx.x * 128;
    __shared__ __align__(16) unsigned short Wlds[4][4096];  // F1h,F1l,F2h,F2l frags
    const int t = threadIdx.x;
    const int lane = t & 63, w = t >> 6;
    const int m = lane & 15, q = lane >> 4;

    // stage W frags: wave w DMAs array w (8 chunks x 1KB)
    const unsigned short* warr = (w == 0) ? F1h : (w == 1) ? F1l : (w == 2) ? F2h : F2l;
    #pragma unroll
    for (int i = 0; i < 8; ++i)
        dma16(warr + i * 512 + lane * 8, &Wlds[w][i * 512]);

    // A-frags: xs = f+h, xp = f*h, split hi/lo bf16
    bf16x8 sh[2][2], sl[2][2], ph[2][2], pl[2][2];
    #pragma unroll
    for (int s = 0; s < 2; ++s) {
        int n = n0 + w * 32 + s * 16 + m;
        const float* fp = feat + (size_t)n * D;
        const float* hp = h_nb + (size_t)n * D;
        #pragma unroll
        for (int kb = 0; kb < 2; ++kb) {
            int d0 = kb * 32 + q * 8;
            float4 f0 = make_float4(0.f, 0.f, 0.f, 0.f), f1 = f0, h0 = f0, h1 = f0;
            if (n < N) {
                f0 = *(const float4*)(fp + d0); f1 = *(const float4*)(fp + d0 + 4);
                h0 = *(const float4*)(hp + d0); h1 = *(const float4*)(hp + d0 + 4);
            }
            float fv[8] = {f0.x, f0.y, f0.z, f0.w, f1.x, f1.y, f1.z, f1.w};
            float hv[8] = {h0.x, h0.y, h0.z, h0.w, h1.x, h1.y, h1.z, h1.w};
            bf16x8 a, b, c2, d2;
            #pragma unroll
            for (int j = 0; j < 8; ++j) {
                float xs = fv[j] + hv[j];
                float xp = fv[j] * hv[j];
                unsigned short hs = f2bf(xs);
                unsigned short hp2 = f2bf(xp);
                a[j]  = (short)hs;
                b[j]  = (short)f2bf(xs - bf2f(hs));
                c2[j] = (short)hp2;
                d2[j] = (short)f2bf(xp - bf2f(hp2));
            }
            sh[s][kb] = a; sl[s][kb] = b; ph[s][kb] = c2; pl[s][kb] = d2;
        }
    }
    __syncthreads();   // drains DMA + publishes Wlds

    f32x4 a1[4][2], a2[4][2];
    #pragma unroll
    for (int c = 0; c < 4; ++c)
        #pragma unroll
        for (int s = 0; s < 2; ++s) {
            a1[c][s] = (f32x4){0.f, 0.f, 0.f, 0.f};
            a2[c][s] = (f32x4){0.f, 0.f, 0.f, 0.f};
        }
    #pragma unroll
    for (int c = 0; c < 4; ++c) {
        bf16x8 b1h[2], b1l[2], b2h[2], b2l[2];
        #pragma unroll
        for (int kb = 0; kb < 2; ++kb) {
            int o = (c * 2 + kb) * 512 + lane * 8;
            b1h[kb] = *(const bf16x8*)&Wlds[0][o];
            b1l[kb] = *(const bf16x8*)&Wlds[1][o];
            b2h[kb] = *(const bf16x8*)&Wlds[2][o];
            b2l[kb] = *(const bf16x8*)&Wlds[3][o];
        }
        #pragma unroll
        for (int kb = 0; kb < 2; ++kb)
            #pragma unroll
            for (int s = 0; s < 2; ++s) {
                a1[c][s] = __builtin_amdgcn_mfma_f32_16x16x32_bf16(sh[s][kb], b1h[kb], a1[c][s], 0, 0, 0);
                a1[c][s] = __builtin_amdgcn_mfma_f32_16x16x32_bf16(sl[s][kb], b1h[kb], a1[c][s], 0, 0, 0);
                a1[c][s] = __builtin_amdgcn_mfma_f32_16x16x32_bf16(sh[s][kb], b1l[kb], a1[c][s], 0, 0, 0);
                a2[c][s] = __builtin_amdgcn_mfma_f32_16x16x32_bf16(ph[s][kb], b2h[kb], a2[c][s], 0, 0, 0);
                a2[c][s] = __builtin_amdgcn_mfma_f32_16x16x32_bf16(pl[s][kb], b2h[kb], a2[c][s], 0, 0, 0);
                a2[c][s] = __builtin_amdgcn_mfma_f32_16x16x32_bf16(ph[s][kb], b2l[kb], a2[c][s], 0, 0, 0);
            }
    }

    // epilogue: leaky-relu both, add, store fp32 (C-layout: row=q*4+i, col=c*16+m)
    #pragma unroll
    for (int s = 0; s < 2; ++s)
        #pragma unroll
        for (int i = 0; i < 4; ++i) {
            int n = n0 + w * 32 + s * 16 + q * 4 + i;
            if (n < N) {
                #pragma unroll
                for (int c = 0; c < 4; ++c) {
                    float o1 = a1[c][s][i];
                    float o2 = a2[c][s][i];
                    o1 = (o1 > 0.f) ? o1 : 0.01f * o1;
                    o2 = (o2 > 0.f) ? o2 : 0.01f * o2;
                    out[(size_t)n * D + c * 16 + m] = o1 + o2;
                }
            }
        }
}

extern "C" void kernel_launch(void* const* d_in, const int* in_sizes, int n_in,
                              void* d_out, int out_size, void* d_ws, size_t ws_size,
                              hipStream_t stream) {
    const float* feat  = (const float*)d_in[0];
    const float* relW  = (const float*)d_in[1];
    const float* relE  = (const float*)d_in[2];
    const float* W1    = (const float*)d_in[3];
    const float* W2    = (const float*)d_in[4];
    const int*   src   = (const int*)d_in[5];
    const int*   dst   = (const int*)d_in[6];
    const int*   etype = (const int*)d_in[7];
    float* out = (float*)d_out;

    const int N = in_sizes[0] / D;
    const int R = in_sizes[2] / D;
    const int E = in_sizes[5];

    char* w = (char*)d_ws;
    size_t off = 0;
    auto alloc = [&](size_t bytes) -> void* {
        void* p = w + off;
        off = (off + bytes + 255) & ~(size_t)255;
        return p;
    };
    unsigned short* varr = (unsigned short*)alloc((size_t)N * R * D * sizeof(unsigned short));
    float* h_nb   = (float*)alloc((size_t)N * D * sizeof(float));
    int* offsets  = (int*)alloc((size_t)(N + 1) * sizeof(int));
    int* tscan    = (int*)alloc((size_t)N * sizeof(int));
    int* cursor   = (int*)alloc((size_t)N * sizeof(int));
    int* deg      = (int*)alloc((size_t)N * sizeof(int));
    int* bsum     = (int*)alloc(2048 * sizeof(int));
    int* bofs     = (int*)alloc(2048 * sizeof(int));
    int* spack    = (int*)alloc((size_t)E * sizeof(int));
    size_t wfrag = (size_t)R * 4 * 2 * 64 * 8;
    unsigned short* B1h = (unsigned short*)alloc(wfrag * sizeof(unsigned short));
    unsigned short* B1l = (unsigned short*)alloc(wfrag * sizeof(unsigned short));
    unsigned short* B2h = (unsigned short*)alloc(wfrag * sizeof(unsigned short));
    unsigned short* B2l = (unsigned short*)alloc(wfrag * sizeof(unsigned short));
    unsigned short* F1h = (unsigned short*)alloc(4096 * sizeof(unsigned short));
    unsigned short* F1l = (unsigned short*)alloc(4096 * sizeof(unsigned short));
    unsigned short* F2h = (unsigned short*)alloc(4096 * sizeof(unsigned short));
    unsigned short* F2l = (unsigned short*)alloc(4096 * sizeof(unsigned short));
    (void)ws_size; (void)n_in; (void)out_size;

    const int NB = (N + 1023) / 1024;

    k_wsplit<<<(2 * R * 512 + 255) / 256, 256, 0, stream>>>(relW, B1h, B1l, B2h, B2l, R);
    k_wsplit2<<<4, 256, 0, stream>>>(W1, W2, F1h, F1l, F2h, F2l);
    hipMemsetAsync(deg, 0, (size_t)N * sizeof(int), stream);
    k_hist<<<(E + 255) / 256, 256, 0, stream>>>(dst, deg, E);
    k_scan1<<<NB, 1024, 0, stream>>>(deg, tscan, bsum, N);
    k_scan2<<<1, 1024, 0, stream>>>(bsum, bofs, NB);
    k_scan3<<<(N + 1 + 255) / 256, 256, 0, stream>>>(tscan, bofs, offsets, cursor, N);
    k_scatter<<<(E + 255) / 256, 256, 0, stream>>>(src, dst, etype, cursor, spack, E);
    k_projv<<<(N + 127) / 128, 256, 0, stream>>>(feat, B1h, B1l, B2h, B2l, relE, varr, N, R);
    k_fused2<<<(N + 3) / 4, 256, 0, stream>>>(varr, feat, offsets, spack, h_nb, N, R);
    k_final<<<(N + 127) / 128, 256, 0, stream>>>(feat, h_nb, F1h, F1l, F2h, F2l, out, N);
}

// Round 9
// 459.852 us; speedup vs baseline: 1.9904x; 1.0190x over previous
//
#include <hip/hip_runtime.h>
#include <math.h>

#define D 64

typedef __attribute__((ext_vector_type(8))) short bf16x8;
typedef __attribute__((ext_vector_type(4))) float f32x4;

static __device__ __forceinline__ unsigned short f2bf(float f) {
    unsigned int u = __float_as_uint(f);
    unsigned int r = (u + 0x7FFFu + ((u >> 16) & 1u)) >> 16;  // RNE
    return (unsigned short)r;
}
static __device__ __forceinline__ float bf2f(unsigned short h) {
    return __uint_as_float(((unsigned int)h) << 16);
}

#if defined(__has_builtin)
#if __has_builtin(__builtin_amdgcn_cvt_pk_bf16_f32)
#define HAVE_PK_BF16 1
#endif
#endif

static __device__ __forceinline__ unsigned int pk2bf(float a, float b) {
#ifdef HAVE_PK_BF16
    auto v = __builtin_amdgcn_cvt_pk_bf16_f32(a, b);   // low=a, high=b
    return *(unsigned int*)&v;
#else
    return (unsigned int)f2bf(a) | ((unsigned int)f2bf(b) << 16);
#endif
}

// tanh(x) = 1 - 2/(e^{2x}+1); inf-safe at extremes (no clamp needed)
static __device__ __forceinline__ float fast_tanh(float x) {
    float e = __expf(2.f * x);
    float r = __builtin_amdgcn_rcpf(e + 1.f);
    return 1.f - 2.f * r;
}

typedef __attribute__((address_space(1))) const unsigned int as1_uint;
typedef __attribute__((address_space(3))) unsigned int as3_uint;
static __device__ __forceinline__ void dma16(const void* g, void* l) {
    // async global->LDS, 16B/lane; LDS dest = uniform base + lane*16
    __builtin_amdgcn_global_load_lds((as1_uint*)g, (as3_uint*)l, 16, 0, 0);
}

// ---------------- pre-split W into MFMA B-fragment-ordered hi/lo bf16 arrays.
// B1 (GEMM1, P=feat@W):   element W[r][d=kb*32+q*8+j][o=c*16+m]
// B2 (GEMM2, V=u@W^T):    element W[r][d=c*16+m][o=kb*32+q*8+j]
// layout: [r][c][kb][lane=q*16+m][j]  -> chunk (r, c*2+kb) = 64 lanes x 16B
__global__ __launch_bounds__(256) void k_wsplit(const float* __restrict__ W,
                                                unsigned short* __restrict__ B1h,
                                                unsigned short* __restrict__ B1l,
                                                unsigned short* __restrict__ B2h,
                                                unsigned short* __restrict__ B2l,
                                                int R) {
    int idx = blockIdx.x * 256 + threadIdx.x;
    int per_g = R * 512;
    if (idx >= 2 * per_g) return;
    int g = idx / per_g;
    int rest = idx % per_g;
    int r = rest >> 9;
    int rest2 = rest & 511;
    int c = rest2 >> 7;
    int kb = (rest2 >> 6) & 1;
    int lane = rest2 & 63;
    int m = lane & 15, q = lane >> 4;
    bf16x8 hv, lv;
    #pragma unroll
    for (int j = 0; j < 8; ++j) {
        float v;
        if (g == 0) v = W[(size_t)r * 4096 + (kb * 32 + q * 8 + j) * 64 + (c * 16 + m)];
        else        v = W[(size_t)r * 4096 + (c * 16 + m) * 64 + (kb * 32 + q * 8 + j)];
        unsigned short h = f2bf(v);
        hv[j] = (short)h;
        lv[j] = (short)f2bf(v - bf2f(h));
    }
    size_t off = ((((size_t)r * 4 + c) * 2 + kb) * 64 + lane) * 8;
    unsigned short* ph = (g == 0) ? B1h : B2h;
    unsigned short* pl = (g == 0) ? B1l : B2l;
    *(bf16x8*)&ph[off] = hv;
    *(bf16x8*)&pl[off] = lv;
}

// ---------------- pre-split W1/W2 (for k_final): out = x @ Wk^T.
__global__ __launch_bounds__(256) void k_wsplit2(const float* __restrict__ W1,
                                                 const float* __restrict__ W2,
                                                 unsigned short* __restrict__ F1h,
                                                 unsigned short* __restrict__ F1l,
                                                 unsigned short* __restrict__ F2h,
                                                 unsigned short* __restrict__ F2l) {
    int idx = blockIdx.x * 256 + threadIdx.x;
    if (idx >= 1024) return;
    int g = idx >> 9;
    int rest2 = idx & 511;
    int c = rest2 >> 7;
    int kb = (rest2 >> 6) & 1;
    int lane = rest2 & 63;
    int m = lane & 15, q = lane >> 4;
    const float* W = g ? W2 : W1;
    bf16x8 hv, lv;
    #pragma unroll
    for (int j = 0; j < 8; ++j) {
        float v = W[(c * 16 + m) * 64 + kb * 32 + q * 8 + j];
        unsigned short h = f2bf(v);
        hv[j] = (short)h;
        lv[j] = (short)f2bf(v - bf2f(h));
    }
    size_t off = (((size_t)c * 2 + kb) * 64 + lane) * 8;
    unsigned short* ph = g ? F2h : F1h;
    unsigned short* pl = g ? F2l : F1l;
    *(bf16x8*)&ph[off] = hv;
    *(bf16x8*)&pl[off] = lv;
}

// ---------------- fused proj+V: single-buffered B LDS (32KB) + per-s Us (8KB)
// = 40KB -> 4 blocks/CU (16 waves). Two barriers per r; DMA stage(r+1) between.
__global__ __launch_bounds__(256, 4) void k_projv(const float* __restrict__ feat,
                                                  const unsigned short* __restrict__ B1h,
                                                  const unsigned short* __restrict__ B1l,
                                                  const unsigned short* __restrict__ B2h,
                                                  const unsigned short* __restrict__ B2l,
                                                  const float* __restrict__ emb,
                                                  unsigned short* __restrict__ V,
                                                  int N, int R) {
    const int n0 = blockIdx.x * 128;
    __shared__ __align__(16) unsigned short Bbuf[32][512];   // 32 KB
    __shared__ __align__(16) unsigned short Us[4][1024];     // 8 KB (2KB/wave, per-s)
    const int t = threadIdx.x;
    const int lane = t & 63, w = t >> 6;
    const int m = lane & 15, q = lane >> 4;

    // ---- A-frags direct from global, split hi/lo in-register
    bf16x8 ah[2][2], al[2][2];
    #pragma unroll
    for (int s = 0; s < 2; ++s) {
        int n = n0 + w * 32 + s * 16 + m;
        const float* rowp = feat + (size_t)n * D;
        #pragma unroll
        for (int kb = 0; kb < 2; ++kb) {
            int d0 = kb * 32 + q * 8;
            float4 v0 = make_float4(0.f, 0.f, 0.f, 0.f), v1 = v0;
            if (n < N) { v0 = *(const float4*)(rowp + d0); v1 = *(const float4*)(rowp + d0 + 4); }
            float vals[8] = {v0.x, v0.y, v0.z, v0.w, v1.x, v1.y, v1.z, v1.w};
            bf16x8 hv, lv;
            #pragma unroll
            for (int j = 0; j < 8; ++j) {
                unsigned short h = f2bf(vals[j]);
                hv[j] = (short)h;
                lv[j] = (short)f2bf(vals[j] - bf2f(h));
            }
            ah[s][kb] = hv; al[s][kb] = lv;
        }
    }

    // wave w DMAs array w (8 chunks x 1KB) for relation r into Bbuf
    const unsigned short* warr = (w == 0) ? B1h : (w == 1) ? B1l : (w == 2) ? B2h : B2l;
    auto stage = [&](int r) {
        const unsigned short* gp = warr + (size_t)r * 4096 + lane * 8;
        #pragma unroll
        for (int i = 0; i < 8; ++i)
            dma16(gp + i * 512, &Bbuf[w * 8 + i][0]);
    };

    stage(0);
    __syncthreads();

    for (int r = 0; r < R; ++r) {
        float em[4];
        #pragma unroll
        for (int c = 0; c < 4; ++c) em[c] = emb[r * 64 + c * 16 + m];

        #pragma unroll
        for (int s = 0; s < 2; ++s) {
            // ---------- GEMM1(s): P = feat @ W_r (3-term split)
            f32x4 acc[4];
            #pragma unroll
            for (int c = 0; c < 4; ++c) acc[c] = (f32x4){0.f, 0.f, 0.f, 0.f};
            #pragma unroll
            for (int c = 0; c < 4; ++c) {
                bf16x8 bh[2], bl[2];
                #pragma unroll
                for (int kb = 0; kb < 2; ++kb) {
                    bh[kb] = *(const bf16x8*)&Bbuf[c * 2 + kb][lane * 8];
                    bl[kb] = *(const bf16x8*)&Bbuf[8 + c * 2 + kb][lane * 8];
                }
                #pragma unroll
                for (int kb = 0; kb < 2; ++kb) {
                    acc[c] = __builtin_amdgcn_mfma_f32_16x16x32_bf16(ah[s][kb], bh[kb], acc[c], 0, 0, 0);
                    acc[c] = __builtin_amdgcn_mfma_f32_16x16x32_bf16(al[s][kb], bh[kb], acc[c], 0, 0, 0);
                    acc[c] = __builtin_amdgcn_mfma_f32_16x16x32_bf16(ah[s][kb], bl[kb], acc[c], 0, 0, 0);
                }
            }

            // ---------- epilogue 1: u = tanh(P+emb) -> swizzled wave-private Us
            #pragma unroll
            for (int c = 0; c < 4; ++c) {
                int o = c * 16 + m;
                int kb2 = o >> 5;
                int q2 = (o >> 3) & 3;
                int j = o & 7;
                int Fb = kb2 * 64 + q2 * 16 + q * 4;
                #pragma unroll
                for (int i = 0; i < 4; i += 2) {
                    float t0 = fast_tanh(acc[c][i] + em[c]);
                    float t1 = fast_tanh(acc[c][i + 1] + em[c]);
                    unsigned int pk = pk2bf(t0, t1);
                    Us[w][((Fb + i) ^ q2) * 8 + j]     = (unsigned short)(pk & 0xFFFF);
                    Us[w][((Fb + i + 1) ^ q2) * 8 + j] = (unsigned short)(pk >> 16);
                }
            }

            // ---------- GEMM2(s): V = u @ W_r^T (2-term split)
            bf16x8 ua[2];
            #pragma unroll
            for (int kb = 0; kb < 2; ++kb) {
                int F = kb * 64 + lane;
                ua[kb] = *(const bf16x8*)&Us[w][(F ^ (lane >> 4)) * 8];
            }
            f32x4 acc2[4];
            #pragma unroll
            for (int c = 0; c < 4; ++c) acc2[c] = (f32x4){0.f, 0.f, 0.f, 0.f};
            #pragma unroll
            for (int c = 0; c < 4; ++c) {
                bf16x8 bh[2], bl[2];
                #pragma unroll
                for (int kb = 0; kb < 2; ++kb) {
                    bh[kb] = *(const bf16x8*)&Bbuf[16 + c * 2 + kb][lane * 8];
                    bl[kb] = *(const bf16x8*)&Bbuf[24 + c * 2 + kb][lane * 8];
                }
                #pragma unroll
                for (int kb = 0; kb < 2; ++kb) {
                    acc2[c] = __builtin_amdgcn_mfma_f32_16x16x32_bf16(ua[kb], bh[kb], acc2[c], 0, 0, 0);
                    acc2[c] = __builtin_amdgcn_mfma_f32_16x16x32_bf16(ua[kb], bl[kb], acc2[c], 0, 0, 0);
                }
            }

            // ---------- store V(s) permuted: Vstore[n][r][m*4+c] (8B/lane)
            #pragma unroll
            for (int i = 0; i < 4; ++i) {
                int n = n0 + w * 32 + s * 16 + q * 4 + i;
                if (n < N) {
                    uint2 pv;
                    pv.x = pk2bf(acc2[0][i], acc2[1][i]);
                    pv.y = pk2bf(acc2[2][i], acc2[3][i]);
                    *(uint2*)&V[((size_t)n * R + r) * 64 + m * 4] = pv;
                }
            }
        }

        __syncthreads();                 // all waves done reading Bbuf for r
        if (r + 1 < R) stage(r + 1);     // DMA next relation into same buffer
        __syncthreads();                 // vmcnt drain -> Bbuf valid for r+1
    }
}

// ---------------- histogram of dst
__global__ __launch_bounds__(256) void k_hist(const int* __restrict__ dst, int* __restrict__ deg, int E) {
    int e = blockIdx.x * 256 + threadIdx.x;
    if (e < E) atomicAdd(&deg[dst[e]], 1);
}

// ---------------- scan step 1
__global__ __launch_bounds__(1024) void k_scan1(const int* __restrict__ deg, int* __restrict__ tscan,
                                                int* __restrict__ bsum, int N) {
    __shared__ int s[1024];
    const int t = threadIdx.x;
    const int i = blockIdx.x * 1024 + t;
    int v = (i < N) ? deg[i] : 0;
    s[t] = v;
    __syncthreads();
    for (int off = 1; off < 1024; off <<= 1) {
        int tmp = (t >= off) ? s[t - off] : 0;
        __syncthreads();
        s[t] += tmp;
        __syncthreads();
    }
    if (i < N) tscan[i] = s[t];
    if (t == 1023) bsum[blockIdx.x] = s[1023];
}

// ---------------- scan step 2
__global__ __launch_bounds__(1024) void k_scan2(const int* __restrict__ bsum, int* __restrict__ bofs, int NB) {
    __shared__ int s[1024];
    const int t = threadIdx.x;
    int carry = 0;
    for (int b0 = 0; b0 < NB; b0 += 1024) {
        int i = b0 + t;
        int v = (i < NB) ? bsum[i] : 0;
        s[t] = v;
        __syncthreads();
        for (int off = 1; off < 1024; off <<= 1) {
            int tmp = (t >= off) ? s[t - off] : 0;
            __syncthreads();
            s[t] += tmp;
            __syncthreads();
        }
        if (i < NB) bofs[i] = carry + s[t] - v;
        int tot = s[1023];
        __syncthreads();
        carry += tot;
    }
}

// ---------------- scan step 3
__global__ __launch_bounds__(256) void k_scan3(const int* __restrict__ tscan, const int* __restrict__ bofs,
                                               int* __restrict__ offsets, int* __restrict__ cursor, int N) {
    int i = blockIdx.x * 256 + threadIdx.x;
    if (i <= N) {
        int v = (i == 0) ? 0 : (tscan[i - 1] + bofs[(i - 1) >> 10]);
        offsets[i] = v;
        if (i < N) cursor[i] = v;
    }
}

// ---------------- scatter edges into dst-sorted order
__global__ __launch_bounds__(256) void k_scatter(const int* __restrict__ src, const int* __restrict__ dst,
                                                 const int* __restrict__ etype, int* __restrict__ cursor,
                                                 int* __restrict__ spack, int E) {
    int e = blockIdx.x * 256 + threadIdx.x;
    if (e < E) {
        int d = dst[e];
        int p = atomicAdd(&cursor[d], 1);
        spack[p] = src[e] | (etype[e] << 20);
    }
}

// ---------------- fused att + softmax + aggregation: 4 edges per wave-iteration.
__global__ __launch_bounds__(256) void k_fused2(const unsigned short* __restrict__ V,
                                                const float* __restrict__ feat,
                                                const int* __restrict__ offsets,
                                                const int* __restrict__ spack,
                                                float* __restrict__ h_nb,
                                                int N, int R) {
    const int lane = threadIdx.x & 63;
    const int wav  = threadIdx.x >> 6;
    const int g    = lane >> 4;
    const int k    = lane & 15;
    const int n = blockIdx.x * 4 + wav;
    __shared__ float vlds[4][1024];
    if (n >= N) return;

    const unsigned int* v32 = (const unsigned int*)(V + (size_t)n * R * D);
    #pragma unroll
    for (int j = 0; j < 8; ++j) {
        int uidx = j * 64 + lane;
        unsigned int u = v32[uidx];
        int r  = uidx >> 5;
        int k2 = uidx & 31;
        int mm = k2 >> 1;
        int cc = (k2 & 1) * 2;
        int o  = cc * 16 + mm;
        vlds[wav][r * 64 + o]      = bf2f((unsigned short)(u & 0xFFFF));
        vlds[wav][r * 64 + o + 16] = bf2f((unsigned short)(u >> 16));
    }

    const int beg = offsets[n], end = offsets[n + 1];
    float m = -INFINITY, l = 0.f;
    float4 acc = make_float4(0.f, 0.f, 0.f, 0.f);

    if (beg < end) {
        int e = beg + g;
        bool ok = e < end;
        int pk = spack[ok ? e : (end - 1)];
        float4 f = *(const float4*)&feat[(size_t)(pk & 0xFFFFF) * D + k * 4];

        for (int i = beg; i < end; i += 4) {
            const int   et  = pk >> 20;
            const float4 fc = f;
            const bool  okc = ok;
            int e2 = i + 4 + g;
            ok = e2 < end;
            pk = spack[ok ? e2 : (end - 1)];
            f = *(const float4*)&feat[(size_t)(pk & 0xFFFFF) * D + k * 4];

            float4 v = *(const float4*)&vlds[wav][et * 64 + k * 4];
            float p = fc.x * v.x + fc.y * v.y + fc.z * v.z + fc.w * v.w;
            p += __shfl_xor(p, 1, 64);
            p += __shfl_xor(p, 2, 64);
            p += __shfl_xor(p, 4, 64);
            p += __shfl_xor(p, 8, 64);
            p = okc ? p : -INFINITY;
            float tmx = fmaxf(p, __shfl_xor(p, 16, 64));
            float nm4 = fmaxf(tmx, __shfl_xor(tmx, 32, 64));
            float nm  = fmaxf(m, nm4);
            float scale = __expf(m - nm);
            float wg    = __expf(p - nm);
            float sw = wg + __shfl_xor(wg, 16, 64);
            sw += __shfl_xor(sw, 32, 64);
            l = l * scale + sw;
            acc.x = acc.x * scale + wg * fc.x;
            acc.y = acc.y * scale + wg * fc.y;
            acc.z = acc.z * scale + wg * fc.z;
            acc.w = acc.w * scale + wg * fc.w;
            m = nm;
        }
        acc.x += __shfl_xor(acc.x, 16, 64);
        acc.y += __shfl_xor(acc.y, 16, 64);
        acc.z += __shfl_xor(acc.z, 16, 64);
        acc.w += __shfl_xor(acc.w, 16, 64);
        acc.x += __shfl_xor(acc.x, 32, 64);
        acc.y += __shfl_xor(acc.y, 32, 64);
        acc.z += __shfl_xor(acc.z, 32, 64);
        acc.w += __shfl_xor(acc.w, 32, 64);
        float inv = 1.f / l;
        acc.x *= inv; acc.y *= inv; acc.z *= inv; acc.w *= inv;
    }
    if (lane < 16)
        *(float4*)&h_nb[(size_t)n * D + k * 4] = acc;
}

// ---------------- final via MFMA: out = lrelu((f+h)@W1^T) + lrelu((f*h)@W2^T)
__global__ __launch_bounds__(256, 2) void k_final(const float* __restrict__ feat,
                                                  const float* __restrict__ h_nb,
                                                  const unsigned short* __restrict__ F1h,
                                                  const unsigned short* __restrict__ F1l,
                                                  const unsigned short* __restrict__ F2h,
                                                  const unsigned short* __restrict__ F2l,
                                                  float* __restrict__ out, int N) {
    const int n0 = blockIdx.x * 128;
    __shared__ __align__(16) unsigned short Wlds[4][4096];
    const int t = threadIdx.x;
    const int lane = t & 63, w = t >> 6;
    const int m = lane & 15, q = lane >> 4;

    const unsigned short* warr = (w == 0) ? F1h : (w == 1) ? F1l : (w == 2) ? F2h : F2l;
    #pragma unroll
    for (int i = 0; i < 8; ++i)
        dma16(warr + i * 512 + lane * 8, &Wlds[w][i * 512]);

    bf16x8 sh[2][2], sl[2][2], ph[2][2], pl[2][2];
    #pragma unroll
    for (int s = 0; s < 2; ++s) {
        int n = n0 + w * 32 + s * 16 + m;
        const float* fp = feat + (size_t)n * D;
        const float* hp = h_nb + (size_t)n * D;
        #pragma unroll
        for (int kb = 0; kb < 2; ++kb) {
            int d0 = kb * 32 + q * 8;
            float4 f0 = make_float4(0.f, 0.f, 0.f, 0.f), f1 = f0, h0 = f0, h1 = f0;
            if (n < N) {
                f0 = *(const float4*)(fp + d0); f1 = *(const float4*)(fp + d0 + 4);
                h0 = *(const float4*)(hp + d0); h1 = *(const float4*)(hp + d0 + 4);
            }
            float fv[8] = {f0.x, f0.y, f0.z, f0.w, f1.x, f1.y, f1.z, f1.w};
            float hv[8] = {h0.x, h0.y, h0.z, h0.w, h1.x, h1.y, h1.z, h1.w};
            bf16x8 a, b, c2, d2;
            #pragma unroll
            for (int j = 0; j < 8; ++j) {
                float xs = fv[j] + hv[j];
                float xp = fv[j] * hv[j];
                unsigned short hs = f2bf(xs);
                unsigned short hp2 = f2bf(xp);
                a[j]  = (short)hs;
                b[j]  = (short)f2bf(xs - bf2f(hs));
                c2[j] = (short)hp2;
                d2[j] = (short)f2bf(xp - bf2f(hp2));
            }
            sh[s][kb] = a; sl[s][kb] = b; ph[s][kb] = c2; pl[s][kb] = d2;
        }
    }
    __syncthreads();

    f32x4 a1[4][2], a2[4][2];
    #pragma unroll
    for (int c = 0; c < 4; ++c)
        #pragma unroll
        for (int s = 0; s < 2; ++s) {
            a1[c][s] = (f32x4){0.f, 0.f, 0.f, 0.f};
            a2[c][s] = (f32x4){0.f, 0.f, 0.f, 0.f};
        }
    #pragma unroll
    for (int c = 0; c < 4; ++c) {
        bf16x8 b1h[2], b1l[2], b2h[2], b2l[2];
        #pragma unroll
        for (int kb = 0; kb < 2; ++kb) {
            int o = (c * 2 + kb) * 512 + lane * 8;
            b1h[kb] = *(const bf16x8*)&Wlds[0][o];
            b1l[kb] = *(const bf16x8*)&Wlds[1][o];
            b2h[kb] = *(const bf16x8*)&Wlds[2][o];
            b2l[kb] = *(const bf16x8*)&Wlds[3][o];
        }
        #pragma unroll
        for (int kb = 0; kb < 2; ++kb)
            #pragma unroll
            for (int s = 0; s < 2; ++s) {
                a1[c][s] = __builtin_amdgcn_mfma_f32_16x16x32_bf16(sh[s][kb], b1h[kb], a1[c][s], 0, 0, 0);
                a1[c][s] = __builtin_amdgcn_mfma_f32_16x16x32_bf16(sl[s][kb], b1h[kb], a1[c][s], 0, 0, 0);
                a1[c][s] = __builtin_amdgcn_mfma_f32_16x16x32_bf16(sh[s][kb], b1l[kb], a1[c][s], 0, 0, 0);
                a2[c][s] = __builtin_amdgcn_mfma_f32_16x16x32_bf16(ph[s][kb], b2h[kb], a2[c][s], 0, 0, 0);
                a2[c][s] = __builtin_amdgcn_mfma_f32_16x16x32_bf16(pl[s][kb], b2h[kb], a2[c][s], 0, 0, 0);
                a2[c][s] = __builtin_amdgcn_mfma_f32_16x16x32_bf16(ph[s][kb], b2l[kb], a2[c][s], 0, 0, 0);
            }
    }

    #pragma unroll
    for (int s = 0; s < 2; ++s)
        #pragma unroll
        for (int i = 0; i < 4; ++i) {
            int n = n0 + w * 32 + s * 16 + q * 4 + i;
            if (n < N) {
                #pragma unroll
                for (int c = 0; c < 4; ++c) {
                    float o1 = a1[c][s][i];
                    float o2 = a2[c][s][i];
                    o1 = (o1 > 0.f) ? o1 : 0.01f * o1;
                    o2 = (o2 > 0.f) ? o2 : 0.01f * o2;
                    out[(size_t)n * D + c * 16 + m] = o1 + o2;
                }
            }
        }
}

extern "C" void kernel_launch(void* const* d_in, const int* in_sizes, int n_in,
                              void* d_out, int out_size, void* d_ws, size_t ws_size,
                              hipStream_t stream) {
    const float* feat  = (const float*)d_in[0];
    const float* relW  = (const float*)d_in[1];
    const float* relE  = (const float*)d_in[2];
    const float* W1    = (const float*)d_in[3];
    const float* W2    = (const float*)d_in[4];
    const int*   src   = (const int*)d_in[5];
    const int*   dst   = (const int*)d_in[6];
    const int*   etype = (const int*)d_in[7];
    float* out = (float*)d_out;

    const int N = in_sizes[0] / D;
    const int R = in_sizes[2] / D;
    const int E = in_sizes[5];

    char* w = (char*)d_ws;
    size_t off = 0;
    auto alloc = [&](size_t bytes) -> void* {
        void* p = w + off;
        off = (off + bytes + 255) & ~(size_t)255;
        return p;
    };
    unsigned short* varr = (unsigned short*)alloc((size_t)N * R * D * sizeof(unsigned short));
    float* h_nb   = (float*)alloc((size_t)N * D * sizeof(float));
    int* offsets  = (int*)alloc((size_t)(N + 1) * sizeof(int));
    int* tscan    = (int*)alloc((size_t)N * sizeof(int));
    int* cursor   = (int*)alloc((size_t)N * sizeof(int));
    int* deg      = (int*)alloc((size_t)N * sizeof(int));
    int* bsum     = (int*)alloc(2048 * sizeof(int));
    int* bofs     = (int*)alloc(2048 * sizeof(int));
    int* spack    = (int*)alloc((size_t)E * sizeof(int));
    size_t wfrag = (size_t)R * 4 * 2 * 64 * 8;
    unsigned short* B1h = (unsigned short*)alloc(wfrag * sizeof(unsigned short));
    unsigned short* B1l = (unsigned short*)alloc(wfrag * sizeof(unsigned short));
    unsigned short* B2h = (unsigned short*)alloc(wfrag * sizeof(unsigned short));
    unsigned short* B2l = (unsigned short*)alloc(wfrag * sizeof(unsigned short));
    unsigned short* F1h = (unsigned short*)alloc(4096 * sizeof(unsigned short));
    unsigned short* F1l = (unsigned short*)alloc(4096 * sizeof(unsigned short));
    unsigned short* F2h = (unsigned short*)alloc(4096 * sizeof(unsigned short));
    unsigned short* F2l = (unsigned short*)alloc(4096 * sizeof(unsigned short));
    (void)ws_size; (void)n_in; (void)out_size;

    const int NB = (N + 1023) / 1024;

    k_wsplit<<<(2 * R * 512 + 255) / 256, 256, 0, stream>>>(relW, B1h, B1l, B2h, B2l, R);
    k_wsplit2<<<4, 256, 0, stream>>>(W1, W2, F1h, F1l, F2h, F2l);
    hipMemsetAsync(deg, 0, (size_t)N * sizeof(int), stream);
    k_hist<<<(E + 255) / 256, 256, 0, stream>>>(dst, deg, E);
    k_scan1<<<NB, 1024, 0, stream>>>(deg, tscan, bsum, N);
    k_scan2<<<1, 1024, 0, stream>>>(bsum, bofs, NB);
    k_scan3<<<(N + 1 + 255) / 256, 256, 0, stream>>>(tscan, bofs, offsets, cursor, N);
    k_scatter<<<(E + 255) / 256, 256, 0, stream>>>(src, dst, etype, cursor, spack, E);
    k_projv<<<(N + 127) / 128, 256, 0, stream>>>(feat, B1h, B1l, B2h, B2l, relE, varr, N, R);
    k_fused2<<<(N + 3) / 4, 256, 0, stream>>>(varr, feat, offsets, spack, h_nb, N, R);
    k_final<<<(N + 127) / 128, 256, 0, stream>>>(feat, h_nb, F1h, F1l, F2h, F2l, out, N);
}